// Round 7
// baseline (309.989 us; speedup 1.0000x reference)
//
#include <hip/hip_runtime.h>
#include <hip/hip_bf16.h>
#include <math.h>

#define NN   8192
#define EE   262144
#define CC   256
#define HH   4

typedef __bf16 bf16;
typedef __bf16 bf16x8 __attribute__((ext_vector_type(8)));
typedef __bf16 bf16x4 __attribute__((ext_vector_type(4)));
typedef __bf16 bf16x2 __attribute__((ext_vector_type(2)));
typedef float  f32x4  __attribute__((ext_vector_type(4)));

static __device__ __forceinline__ bf16 f2bf(float f) { return (bf16)f; }

// packed f32x2 -> bf16x2 in one dword (v_cvt_pk_bf16_f32)
static __device__ __forceinline__ unsigned pk2(float a, float b) {
    __hip_bfloat162 h = __float22bfloat162_rn(float2{a, b});
    return *reinterpret_cast<unsigned*>(&h);
}

// ---------------------------------------------------------------- fused prep
// x->bf16 (grid-stride), 4 weight cvts, and degree atomics in ONE launch.
// blocks: [0,2048) xcvt | [2048,2816) ipw | [2816,3072) opw | [3072,3328) fcw
//         [3328,3584) wlT | [3584,4608) degree
__global__ void prep_all(const float* __restrict__ x, bf16* __restrict__ xb,
                         const float* __restrict__ ipw, const float* __restrict__ opw,
                         const float* __restrict__ fcw, const float* __restrict__ wloc,
                         bf16* __restrict__ ipwb, bf16* __restrict__ opwb,
                         bf16* __restrict__ fcwb, bf16* __restrict__ wlTb,
                         const int* __restrict__ adj, int* __restrict__ ideg) {
    int b = blockIdx.x, t = threadIdx.x;
    if (b < 2048) {
        for (int i = b * 256 + t; i < NN * CC; i += 2048 * 256) xb[i] = f2bf(x[i]);
    } else if (b < 2816) { int i = (b - 2048) * 256 + t; ipwb[i] = f2bf(ipw[i]); }
    else if (b < 3072)   { int i = (b - 2816) * 256 + t; opwb[i] = f2bf(opw[i]); }
    else if (b < 3328)   { int i = (b - 3072) * 256 + t; fcwb[i] = f2bf(fcw[i]); }
    else if (b < 3584)   { int n = b - 3328;             wlTb[n * 256 + t] = f2bf(wloc[t * 256 + n]); }
    else {
        int e = (b - 3584) * 256 + t;
        if (e < EE) atomicAdd(&ideg[adj[EE + e]], 1);
    }
}

// ---------------------------------------------------------------- K/V fragment prepack (fused)
// Kpk[((h*512 + kt)*2 + c)*512 + lane*8 + j] = K_h[key][d]  (key chunk-permuted)
// Vpk[((h*256 + kc)*4 + nt)*512 + lane*8 + j] = V_h[key = kc*32 + quad*8 + j][d = nt*16 + l15]
__global__ __launch_bounds__(256) void build_kv(const bf16* __restrict__ qkv,
                                                bf16* __restrict__ Kpk,
                                                bf16* __restrict__ Vpk) {
    __shared__ bf16 tl[64][72];
    const int bx = blockIdx.x;     // 64-key tile
    const int h  = blockIdx.y;
    const int tid = threadIdx.x;
    // ---- K
    #pragma unroll
    for (int i = 0; i < 2; i++) {
        int u = tid + i * 256;
        int key = u >> 3, g = u & 7;
        *reinterpret_cast<bf16x8*>(&tl[key][g * 8]) =
            *reinterpret_cast<const bf16x8*>(qkv + (size_t)(bx * 64 + key) * 768 + 256 + h * 64 + g * 8);
    }
    __syncthreads();
    #pragma unroll
    for (int i = 0; i < 2; i++) {
        int ee = tid + i * 256;
        int l15 = ee & 15, quad = (ee >> 4) & 3, c = (ee >> 6) & 1, ktl = ee >> 7;
        int key_local = (ktl >> 1) * 32 + (l15 >> 2) * 8 + (ktl & 1) * 4 + (l15 & 3);
        bf16x8 v = *reinterpret_cast<const bf16x8*>(&tl[key_local][c * 32 + quad * 8]);
        *reinterpret_cast<bf16x8*>(Kpk + ((size_t)((h * 512 + bx * 4 + ktl) * 2 + c)) * 512
                                       + (quad * 16 + l15) * 8) = v;
    }
    __syncthreads();
    // ---- V
    #pragma unroll
    for (int i = 0; i < 2; i++) {
        int u = tid + i * 256;
        int key = u >> 3, g = u & 7;
        *reinterpret_cast<bf16x8*>(&tl[key][g * 8]) =
            *reinterpret_cast<const bf16x8*>(qkv + (size_t)(bx * 64 + key) * 768 + 512 + h * 64 + g * 8);
    }
    __syncthreads();
    #pragma unroll
    for (int i = 0; i < 2; i++) {
        int ee = tid + i * 256;
        int l15 = ee & 15, quad = (ee >> 4) & 3, nt = (ee >> 6) & 3, kcl = ee >> 8;
        bf16x8 v;
        #pragma unroll
        for (int j = 0; j < 8; j++) v[j] = tl[kcl * 32 + quad * 8 + j][nt * 16 + l15];
        *reinterpret_cast<bf16x8*>(Vpk + ((size_t)((h * 256 + bx * 2 + kcl) * 4 + nt)) * 512
                                       + (quad * 16 + l15) * 8) = v;
    }
}

// ---------------------------------------------------------------- GCN conv (CSR gather)
__global__ __launch_bounds__(256) void scan_offsets(const int* __restrict__ ideg,
        int* __restrict__ off, int* __restrict__ cursor, float* __restrict__ rs) {
    __shared__ int ps[256];
    const int tid = threadIdx.x;
    const int base = tid * 32;
    int loc[32];
    int s = 0;
    #pragma unroll
    for (int i = 0; i < 32; i++) { loc[i] = s; s += ideg[base + i]; }
    ps[tid] = s;
    __syncthreads();
    for (int d = 1; d < 256; d <<= 1) {
        int v = (tid >= d) ? ps[tid - d] : 0;
        __syncthreads();
        ps[tid] += v;
        __syncthreads();
    }
    int excl = ps[tid] - s;
    #pragma unroll
    for (int i = 0; i < 32; i++) {
        int o = excl + loc[i];
        off[base + i] = o;
        cursor[base + i] = o;
        int dg = ideg[base + i];
        rs[base + i] = dg > 0 ? rsqrtf((float)dg) : 0.f;
    }
    if (tid == 255) off[8192] = excl + s;
}

__global__ void fill_csr(const int* __restrict__ adj, int* __restrict__ cursor,
                         int* __restrict__ csr) {
    int e = blockIdx.x * 256 + threadIdx.x;
    if (e < EE) {
        int col = adj[EE + e];
        int pos = atomicAdd(&cursor[col], 1);
        csr[pos] = adj[e];
    }
}

// block = dest node; two half-blocks stream alternate edges; bf16 x, packed 2-ch loads
__global__ __launch_bounds__(256) void gcn_gather2(const bf16* __restrict__ xb,
        const int* __restrict__ csr, const int* __restrict__ off,
        const float* __restrict__ rs, bf16* __restrict__ hib) {
    const int col = blockIdx.x;
    const int t = threadIdx.x;
    const int half = t >> 7;
    const int j = t & 127;
    const int o = off[col];
    const int cnt = off[col + 1] - o;
    const float rsc = rs[col];
    float a0 = 0.f, a1 = 0.f;
    for (int e = half; e < cnt; e += 2) {
        int r = csr[o + e];
        float v = rsc * rs[r];
        unsigned u = ((const unsigned*)(xb + (size_t)r * CC))[j];
        a0 += __uint_as_float(u << 16) * v;
        a1 += __uint_as_float(u & 0xffff0000u) * v;
    }
    __shared__ float red[512];
    red[half * 256 + 2 * j]     = a0;
    red[half * 256 + 2 * j + 1] = a1;
    __syncthreads();
    if (t < 128) {
        float s0 = red[2 * t]     + red[256 + 2 * t];
        float s1 = red[2 * t + 1] + red[256 + 2 * t + 1];
        bf16x2 pk; pk[0] = f2bf(s0); pk[1] = f2bf(s1);
        ((bf16x2*)(hib + (size_t)col * CC))[t] = pk;
    }
}

// ---------------------------------------------------------------- BT GEMM
__global__ __launch_bounds__(256) void gemm_bt(
        const bf16* __restrict__ A, const bf16* __restrict__ W,
        const float* __restrict__ bias,
        float* __restrict__ outF, bf16* __restrict__ outB,
        int M, int N, int K) {
    const int tid  = threadIdx.x;
    const int wave = tid >> 6;
    const int lane = tid & 63;
    const int quad = lane >> 4;
    const int l15  = lane & 15;
    const int m0 = blockIdx.x * 128;
    const int n0 = blockIdx.y * 64;

    __shared__ bf16 Alds[128][72];
    __shared__ bf16 Wlds[64][72];

    f32x4 acc[2][4];
    #pragma unroll
    for (int mt = 0; mt < 2; mt++)
        #pragma unroll
        for (int nt = 0; nt < 4; nt++)
            acc[mt][nt] = (f32x4){0.f, 0.f, 0.f, 0.f};

    for (int k0 = 0; k0 < K; k0 += 64) {
        #pragma unroll
        for (int i = 0; i < 4; i++) {
            int u = tid + i * 256;
            int r = u >> 3;
            int cp = u & 7;
            *reinterpret_cast<bf16x8*>(&Alds[r][cp * 8]) =
                *reinterpret_cast<const bf16x8*>(A + (size_t)(m0 + r) * K + k0 + cp * 8);
        }
        #pragma unroll
        for (int i = 0; i < 2; i++) {
            int u = tid + i * 256;
            int r = u >> 3;
            int cp = u & 7;
            *reinterpret_cast<bf16x8*>(&Wlds[r][cp * 8]) =
                *reinterpret_cast<const bf16x8*>(W + (size_t)(n0 + r) * K + k0 + cp * 8);
        }
        __syncthreads();
        #pragma unroll
        for (int c = 0; c < 2; c++) {
            bf16x8 af[2], wf[4];
            #pragma unroll
            for (int mt = 0; mt < 2; mt++)
                af[mt] = *reinterpret_cast<const bf16x8*>(&Alds[wave * 32 + mt * 16 + l15][c * 32 + quad * 8]);
            #pragma unroll
            for (int nt = 0; nt < 4; nt++)
                wf[nt] = *reinterpret_cast<const bf16x8*>(&Wlds[nt * 16 + l15][c * 32 + quad * 8]);
            #pragma unroll
            for (int mt = 0; mt < 2; mt++)
                #pragma unroll
                for (int nt = 0; nt < 4; nt++)
                    acc[mt][nt] = __builtin_amdgcn_mfma_f32_16x16x32_bf16(af[mt], wf[nt], acc[mt][nt], 0, 0, 0);
        }
        __syncthreads();
    }
    #pragma unroll
    for (int mt = 0; mt < 2; mt++)
        #pragma unroll
        for (int nt = 0; nt < 4; nt++)
            #pragma unroll
            for (int r = 0; r < 4; r++) {
                int m = m0 + wave * 32 + mt * 16 + quad * 4 + r;
                int n = n0 + nt * 16 + l15;
                float v = acc[mt][nt][r];
                if (bias) v += bias[n];
                if (outF) outF[(size_t)m * N + n] = v;
                else      outB[(size_t)m * N + n] = f2bf(v);
            }
}

// ---------------------------------------------------------------- flash attention v7
// Zero-LDS main loop, m = 0 (see v6 rationale), key range split 2-way across
// blocks (grid 1024 = 4 blocks/CU, LDS allows 3 resident) so the VALU-bound
// exp2 pipeline overlaps across 3 waves/SIMD instead of 2. Single-buffered
// K/V fragments (fewer live VGPRs; __launch_bounds__(256,3) caps at 170).
// With m==0 the cross-block merge is a plain sum of (O, l) partials.
__global__ __launch_bounds__(256, 3) void flash_attn7(const bf16* __restrict__ qkv,
                                                      const bf16* __restrict__ Kpk,
                                                      const bf16* __restrict__ Vpk,
                                                      bf16* __restrict__ Opart,
                                                      float* __restrict__ lpart) {
    const int tid  = threadIdx.x;
    const int w    = tid >> 6;
    const int lane = tid & 63;
    const int quad = lane >> 4;
    const int l15  = lane & 15;
    const int bx = blockIdx.x;
    const int h    = bx & 3;
    const int qb   = (bx >> 2) & 127;
    const int half = bx >> 9;
    const int qbase = qb * 64;

    __shared__ bf16 Osh[4][64][68];
    __shared__ float lsh[4][64];

    // Q B-frags (n=q=l15, k=d=quad*8+j), prescaled by log2(e)/8
    const float qs = 0.180336880f;
    bf16x8 qf[4][2];
    #pragma unroll
    for (int qt = 0; qt < 4; qt++)
        #pragma unroll
        for (int c = 0; c < 2; c++) {
            bf16x8 raw = *reinterpret_cast<const bf16x8*>(
                qkv + (size_t)(qbase + qt * 16 + l15) * 768 + h * 64 + c * 32 + quad * 8);
            #pragma unroll
            for (int j = 0; j < 8; j++) qf[qt][c][j] = f2bf((float)raw[j] * qs);
        }

    const bf16* Kb = Kpk + (size_t)h * 524288 + lane * 8;
    const bf16* Vb = Vpk + (size_t)h * 524288 + lane * 8;
    const int cbase = half * 128 + w;          // this wave's first 32-key chunk

    f32x4 oacc[4][4];
    #pragma unroll
    for (int qt = 0; qt < 4; qt++)
        #pragma unroll
        for (int nt = 0; nt < 4; nt++) oacc[qt][nt] = (f32x4){0.f, 0.f, 0.f, 0.f};
    f32x4 lacc[4];
    #pragma unroll
    for (int qt = 0; qt < 4; qt++) lacc[qt] = (f32x4){0.f, 0.f, 0.f, 0.f};
    bf16x8 onesf;
    #pragma unroll
    for (int j = 0; j < 8; j++) onesf[j] = f2bf(1.0f);
    const f32x4 z4 = (f32x4){0.f, 0.f, 0.f, 0.f};

    for (int i = 0; i < 32; i++) {
        const int kc = cbase + i * 4;          // <= 128+3+124 = 255: always in range
        bf16x8 kf[2][2], vf[4];
        #pragma unroll
        for (int s = 0; s < 2; s++)
            #pragma unroll
            for (int c = 0; c < 2; c++)
                kf[s][c] = *reinterpret_cast<const bf16x8*>(Kb + kc * 2048 + s * 1024 + c * 512);
        #pragma unroll
        for (int nt = 0; nt < 4; nt++)
            vf[nt] = *reinterpret_cast<const bf16x8*>(Vb + kc * 2048 + nt * 512);

        f32x4 sacc[2][4];
        #pragma unroll
        for (int s = 0; s < 2; s++)
            #pragma unroll
            for (int qt = 0; qt < 4; qt++) {
                sacc[s][qt] = __builtin_amdgcn_mfma_f32_16x16x32_bf16(kf[s][0], qf[qt][0], z4, 0, 0, 0);
                sacc[s][qt] = __builtin_amdgcn_mfma_f32_16x16x32_bf16(kf[s][1], qf[qt][1], sacc[s][qt], 0, 0, 0);
            }
        #pragma unroll
        for (int qt = 0; qt < 4; qt++) {
            float e0 = __builtin_amdgcn_exp2f(sacc[0][qt][0]);
            float e1 = __builtin_amdgcn_exp2f(sacc[0][qt][1]);
            float e2 = __builtin_amdgcn_exp2f(sacc[0][qt][2]);
            float e3 = __builtin_amdgcn_exp2f(sacc[0][qt][3]);
            float e4 = __builtin_amdgcn_exp2f(sacc[1][qt][0]);
            float e5 = __builtin_amdgcn_exp2f(sacc[1][qt][1]);
            float e6 = __builtin_amdgcn_exp2f(sacc[1][qt][2]);
            float e7 = __builtin_amdgcn_exp2f(sacc[1][qt][3]);
            union { bf16x8 v; unsigned u[4]; } pu;
            pu.u[0] = pk2(e0, e1);
            pu.u[1] = pk2(e2, e3);
            pu.u[2] = pk2(e4, e5);
            pu.u[3] = pk2(e6, e7);
            #pragma unroll
            for (int nt = 0; nt < 4; nt++)
                oacc[qt][nt] = __builtin_amdgcn_mfma_f32_16x16x32_bf16(pu.v, vf[nt], oacc[qt][nt], 0, 0, 0);
            lacc[qt] = __builtin_amdgcn_mfma_f32_16x16x32_bf16(pu.v, onesf, lacc[qt], 0, 0, 0);
        }
    }

    // ---- in-block 4-wave merge (plain sums; m == 0 everywhere)
    #pragma unroll
    for (int qt = 0; qt < 4; qt++)
        #pragma unroll
        for (int nt = 0; nt < 4; nt++)
            #pragma unroll
            for (int r = 0; r < 4; r++)
                Osh[w][qt * 16 + quad * 4 + r][nt * 16 + l15] = f2bf(oacc[qt][nt][r]);
    if (l15 == 0) {
        #pragma unroll
        for (int qt = 0; qt < 4; qt++)
            #pragma unroll
            for (int r = 0; r < 4; r++)
                lsh[w][qt * 16 + quad * 4 + r] = lacc[qt][r];
    }
    __syncthreads();

    const int q = w * 16 + l15;
    const size_t ob = (size_t)half * 2097152 + ((size_t)(h * 128 + qb) * 64 + q) * 64;
    if (quad == 0)
        lpart[half * 32768 + (h * 128 + qb) * 64 + q] =
            lsh[0][q] + lsh[1][q] + lsh[2][q] + lsh[3][q];
    #pragma unroll
    for (int gg = 0; gg < 4; gg++) {
        int d0 = gg * 16 + quad * 4;
        f32x4 acc = (f32x4){0.f, 0.f, 0.f, 0.f};
        #pragma unroll
        for (int v = 0; v < 4; v++) {
            bf16x4 ov = *reinterpret_cast<const bf16x4*>(&Osh[v][q][d0]);
            #pragma unroll
            for (int i = 0; i < 4; i++) acc[i] += (float)ov[i];
        }
        bf16x4 obv;
        #pragma unroll
        for (int i = 0; i < 4; i++) obv[i] = f2bf(acc[i]);
        *reinterpret_cast<bf16x4*>(Opart + ob + d0) = obv;
    }
}

// merge the two key-half partials: attnO = (O0+O1)/(l0+l1). grid 512 (= h*128+qb)
__global__ __launch_bounds__(256) void attn_merge(const bf16* __restrict__ Opart,
                                                  const float* __restrict__ lpart,
                                                  bf16* __restrict__ attnO) {
    const int b = blockIdx.x;
    const int h = b >> 7;
    const int qb = b & 127;
    const int t = threadIdx.x;
    const int q = t >> 2;            // 0..63
    const int dg = t & 3;            // d = dg*16
    const float linv = 1.f / (lpart[b * 64 + q] + lpart[32768 + b * 64 + q]);
    const bf16* p0 = Opart + ((size_t)b * 64 + q) * 64 + dg * 16;
    const bf16* p1 = p0 + 2097152;
    bf16x8 a0 = *reinterpret_cast<const bf16x8*>(p0);
    bf16x8 a1 = *reinterpret_cast<const bf16x8*>(p0 + 8);
    bf16x8 b0 = *reinterpret_cast<const bf16x8*>(p1);
    bf16x8 b1 = *reinterpret_cast<const bf16x8*>(p1 + 8);
    bf16x8 o0, o1;
    #pragma unroll
    for (int i = 0; i < 8; i++) {
        o0[i] = f2bf(((float)a0[i] + (float)b0[i]) * linv);
        o1[i] = f2bf(((float)a1[i] + (float)b1[i]) * linv);
    }
    bf16* dst = attnO + (size_t)(qb * 64 + q) * CC + h * 64 + dg * 16;
    *reinterpret_cast<bf16x8*>(dst) = o0;
    *reinterpret_cast<bf16x8*>(dst + 8) = o1;
}

// ---------------------------------------------------------------- LN + combine (wave/row)
__global__ __launch_bounds__(256) void ln_combine2(
        const float* __restrict__ x, const float* __restrict__ aproj,
        const float* __restrict__ local, const float* __restrict__ g,
        const float* __restrict__ b, const float* __restrict__ alpha_p,
        bf16* __restrict__ comb) {
    const int row = blockIdx.x * 4 + (threadIdx.x >> 6);
    const int lane = threadIdx.x & 63;
    const f32x4 xv = ((const f32x4*)(x + (size_t)row * CC))[lane];
    const f32x4 av = ((const f32x4*)(aproj + (size_t)row * CC))[lane];
    f32x4 v = xv + av;
    float s = v[0] + v[1] + v[2] + v[3];
    #pragma unroll
    for (int off = 1; off < 64; off <<= 1) s += __shfl_xor(s, off);
    float mu = s * (1.f / CC);
    f32x4 d = v - mu;
    float ss = d[0] * d[0] + d[1] * d[1] + d[2] * d[2] + d[3] * d[3];
    #pragma unroll
    for (int off = 1; off < 64; off <<= 1) ss += __shfl_xor(ss, off);
    float rstd = rsqrtf(ss * (1.f / CC) + 1e-5f);
    const f32x4 gv = ((const f32x4*)g)[lane];
    const f32x4 bv = ((const f32x4*)b)[lane];
    const f32x4 lv = ((const f32x4*)(local + (size_t)row * CC))[lane];
    float wgt = 1.f / (1.f + __expf(-alpha_p[0]));
    bf16x4 o;
    #pragma unroll
    for (int i = 0; i < 4; i++)
        o[i] = f2bf(wgt * lv[i] + (1.f - wgt) * (d[i] * rstd * gv[i] + bv[i]));
    ((bf16x4*)(comb + (size_t)row * CC))[lane] = o;
}

// ---------------------------------------------------------------- launch
extern "C" void kernel_launch(void* const* d_in, const int* in_sizes, int n_in,
                              void* d_out, int out_size, void* d_ws, size_t ws_size,
                              hipStream_t stream) {
    (void)in_sizes; (void)n_in; (void)out_size; (void)ws_size;
    const float* x    = (const float*)d_in[0];
    const int*   adj  = (const int*)d_in[1];
    const float* wloc = (const float*)d_in[2];
    const float* ipw  = (const float*)d_in[3];
    const float* ipb  = (const float*)d_in[4];
    const float* opw  = (const float*)d_in[5];
    const float* opb  = (const float*)d_in[6];
    const float* lng  = (const float*)d_in[7];
    const float* lnb  = (const float*)d_in[8];
    const float* alp  = (const float*)d_in[9];
    const float* fcw  = (const float*)d_in[10];
    const float* fcb  = (const float*)d_in[11];
    float* out = (float*)d_out;

    char* p = (char*)d_ws;
    int*   ideg   = (int*)p;    p += (size_t)NN * 4;
    int*   off    = (int*)p;    p += (size_t)(NN + 1) * 4;
    int*   cursor = (int*)p;    p += (size_t)NN * 4;
    float* rs     = (float*)p;  p += (size_t)NN * 4;
    int*   csr    = (int*)p;    p += (size_t)EE * 4;
    bf16* xb    = (bf16*)p;   p += (size_t)NN * CC * 2;
    bf16* hib   = (bf16*)p;   p += (size_t)NN * CC * 2;
    bf16* ipwb  = (bf16*)p;   p += (size_t)768 * 256 * 2;
    bf16* wlTb  = (bf16*)p;   p += (size_t)256 * 256 * 2;
    bf16* opwb  = (bf16*)p;   p += (size_t)256 * 256 * 2;
    bf16* fcwb  = (bf16*)p;   p += (size_t)256 * 256 * 2;
    bf16* qkvb  = (bf16*)p;   p += (size_t)NN * 768 * 2;
    bf16* Kpk   = (bf16*)p;   p += (size_t)HH * 512 * 2 * 512 * 2;
    bf16* Vpk   = (bf16*)p;   p += (size_t)HH * 256 * 4 * 512 * 2;
    bf16* aOb   = (bf16*)p;   p += (size_t)NN * CC * 2;
    float* aprj = (float*)p;  p += (size_t)NN * CC * 4;
    float* locl = (float*)p;  p += (size_t)NN * CC * 4;
    bf16* comb  = (bf16*)p;   p += (size_t)NN * CC * 2;
    // flash partials alias later-written buffers (no overlap in lifetime):
    bf16*  Opart = (bf16*)aprj;     // 8 MB: flash7 -> attn_merge, then aprj gemm overwrites
    float* lpart = (float*)locl;    // 256 KB: same pattern

    hipMemsetAsync(ideg, 0, (size_t)NN * 4, stream);

    prep_all<<<4608, 256, 0, stream>>>(x, xb, ipw, opw, fcw, wloc, ipwb, opwb, fcwb, wlTb, adj, ideg);
    scan_offsets<<<1, 256, 0, stream>>>(ideg, off, cursor, rs);
    fill_csr<<<EE / 256, 256, 0, stream>>>(adj, cursor, csr);
    gcn_gather2<<<NN, 256, 0, stream>>>(xb, csr, off, rs, hib);

    gemm_bt<<<dim3(NN / 128, 768 / 64), 256, 0, stream>>>(xb, ipwb, ipb, nullptr, qkvb, NN, 768, 256);
    build_kv<<<dim3(NN / 64, HH), 256, 0, stream>>>(qkvb, Kpk, Vpk);
    flash_attn7<<<1024, 256, 0, stream>>>(qkvb, Kpk, Vpk, Opart, lpart);
    attn_merge<<<512, 256, 0, stream>>>(Opart, lpart, aOb);
    gemm_bt<<<dim3(NN / 128, 256 / 64), 256, 0, stream>>>(aOb, opwb, opb, aprj, nullptr, NN, 256, 256);
    gemm_bt<<<dim3(NN / 128, 256 / 64), 256, 0, stream>>>(hib, wlTb, nullptr, locl, nullptr, NN, 256, 256);
    ln_combine2<<<NN / 4, 256, 0, stream>>>(x, aprj, locl, lng, lnb, alp, comb);
    gemm_bt<<<dim3(NN / 128, 256 / 64), 256, 0, stream>>>(comb, fcwb, fcb, out, nullptr, NN, 256, 256);
}

// Round 9
// 305.003 us; speedup vs baseline: 1.0163x; 1.0163x over previous
//
#include <hip/hip_runtime.h>
#include <hip/hip_bf16.h>
#include <math.h>

#define NN   8192
#define EE   262144
#define CC   256
#define HH   4

typedef __bf16 bf16;
typedef __bf16 bf16x8 __attribute__((ext_vector_type(8)));
typedef __bf16 bf16x4 __attribute__((ext_vector_type(4)));
typedef __bf16 bf16x2 __attribute__((ext_vector_type(2)));
typedef float  f32x4  __attribute__((ext_vector_type(4)));

static __device__ __forceinline__ bf16 f2bf(float f) { return (bf16)f; }

// packed f32x2 -> bf16x2 in one dword (v_cvt_pk_bf16_f32)
static __device__ __forceinline__ unsigned pk2(float a, float b) {
    __hip_bfloat162 h = __float22bfloat162_rn(float2{a, b});
    return *reinterpret_cast<unsigned*>(&h);
}

// ---------------------------------------------------------------- fused prep
__global__ void prep_all(const float* __restrict__ x, bf16* __restrict__ xb,
                         const float* __restrict__ ipw, const float* __restrict__ opw,
                         const float* __restrict__ fcw, const float* __restrict__ wloc,
                         bf16* __restrict__ ipwb, bf16* __restrict__ opwb,
                         bf16* __restrict__ fcwb, bf16* __restrict__ wlTb,
                         const int* __restrict__ adj, int* __restrict__ ideg) {
    int b = blockIdx.x, t = threadIdx.x;
    if (b < 2048) {
        for (int i = b * 256 + t; i < NN * CC; i += 2048 * 256) xb[i] = f2bf(x[i]);
    } else if (b < 2816) { int i = (b - 2048) * 256 + t; ipwb[i] = f2bf(ipw[i]); }
    else if (b < 3072)   { int i = (b - 2816) * 256 + t; opwb[i] = f2bf(opw[i]); }
    else if (b < 3328)   { int i = (b - 3072) * 256 + t; fcwb[i] = f2bf(fcw[i]); }
    else if (b < 3584)   { int n = b - 3328;             wlTb[n * 256 + t] = f2bf(wloc[t * 256 + n]); }
    else {
        int e = (b - 3584) * 256 + t;
        if (e < EE) atomicAdd(&ideg[adj[EE + e]], 1);
    }
}

// ---------------------------------------------------------------- K/V fragment prepack (fused)
__global__ __launch_bounds__(256) void build_kv(const bf16* __restrict__ qkv,
                                                bf16* __restrict__ Kpk,
                                                bf16* __restrict__ Vpk) {
    __shared__ bf16 tl[64][72];
    const int bx = blockIdx.x;     // 64-key tile
    const int h  = blockIdx.y;
    const int tid = threadIdx.x;
    // ---- K
    #pragma unroll
    for (int i = 0; i < 2; i++) {
        int u = tid + i * 256;
        int key = u >> 3, g = u & 7;
        *reinterpret_cast<bf16x8*>(&tl[key][g * 8]) =
            *reinterpret_cast<const bf16x8*>(qkv + (size_t)(bx * 64 + key) * 768 + 256 + h * 64 + g * 8);
    }
    __syncthreads();
    #pragma unroll
    for (int i = 0; i < 2; i++) {
        int ee = tid + i * 256;
        int l15 = ee & 15, quad = (ee >> 4) & 3, c = (ee >> 6) & 1, ktl = ee >> 7;
        int key_local = (ktl >> 1) * 32 + (l15 >> 2) * 8 + (ktl & 1) * 4 + (l15 & 3);
        bf16x8 v = *reinterpret_cast<const bf16x8*>(&tl[key_local][c * 32 + quad * 8]);
        *reinterpret_cast<bf16x8*>(Kpk + ((size_t)((h * 512 + bx * 4 + ktl) * 2 + c)) * 512
                                       + (quad * 16 + l15) * 8) = v;
    }
    __syncthreads();
    // ---- V
    #pragma unroll
    for (int i = 0; i < 2; i++) {
        int u = tid + i * 256;
        int key = u >> 3, g = u & 7;
        *reinterpret_cast<bf16x8*>(&tl[key][g * 8]) =
            *reinterpret_cast<const bf16x8*>(qkv + (size_t)(bx * 64 + key) * 768 + 512 + h * 64 + g * 8);
    }
    __syncthreads();
    #pragma unroll
    for (int i = 0; i < 2; i++) {
        int ee = tid + i * 256;
        int l15 = ee & 15, quad = (ee >> 4) & 3, nt = (ee >> 6) & 3, kcl = ee >> 8;
        bf16x8 v;
        #pragma unroll
        for (int j = 0; j < 8; j++) v[j] = tl[kcl * 32 + quad * 8 + j][nt * 16 + l15];
        *reinterpret_cast<bf16x8*>(Vpk + ((size_t)((h * 256 + bx * 2 + kcl) * 4 + nt)) * 512
                                       + (quad * 16 + l15) * 8) = v;
    }
}

// ---------------------------------------------------------------- GCN conv (CSR gather)
__global__ __launch_bounds__(256) void scan_offsets(const int* __restrict__ ideg,
        int* __restrict__ off, int* __restrict__ cursor, float* __restrict__ rs) {
    __shared__ int ps[256];
    const int tid = threadIdx.x;
    const int base = tid * 32;
    int loc[32];
    int s = 0;
    #pragma unroll
    for (int i = 0; i < 32; i++) { loc[i] = s; s += ideg[base + i]; }
    ps[tid] = s;
    __syncthreads();
    for (int d = 1; d < 256; d <<= 1) {
        int v = (tid >= d) ? ps[tid - d] : 0;
        __syncthreads();
        ps[tid] += v;
        __syncthreads();
    }
    int excl = ps[tid] - s;
    #pragma unroll
    for (int i = 0; i < 32; i++) {
        int o = excl + loc[i];
        off[base + i] = o;
        cursor[base + i] = o;
        int dg = ideg[base + i];
        rs[base + i] = dg > 0 ? rsqrtf((float)dg) : 0.f;
    }
    if (tid == 255) off[8192] = excl + s;
}

__global__ void fill_csr(const int* __restrict__ adj, int* __restrict__ cursor,
                         int* __restrict__ csr) {
    int e = blockIdx.x * 256 + threadIdx.x;
    if (e < EE) {
        int col = adj[EE + e];
        int pos = atomicAdd(&cursor[col], 1);
        csr[pos] = adj[e];
    }
}

__global__ __launch_bounds__(256) void gcn_gather2(const bf16* __restrict__ xb,
        const int* __restrict__ csr, const int* __restrict__ off,
        const float* __restrict__ rs, bf16* __restrict__ hib) {
    const int col = blockIdx.x;
    const int t = threadIdx.x;
    const int half = t >> 7;
    const int j = t & 127;
    const int o = off[col];
    const int cnt = off[col + 1] - o;
    const float rsc = rs[col];
    float a0 = 0.f, a1 = 0.f;
    for (int e = half; e < cnt; e += 2) {
        int r = csr[o + e];
        float v = rsc * rs[r];
        unsigned u = ((const unsigned*)(xb + (size_t)r * CC))[j];
        a0 += __uint_as_float(u << 16) * v;
        a1 += __uint_as_float(u & 0xffff0000u) * v;
    }
    __shared__ float red[512];
    red[half * 256 + 2 * j]     = a0;
    red[half * 256 + 2 * j + 1] = a1;
    __syncthreads();
    if (t < 128) {
        float s0 = red[2 * t]     + red[256 + 2 * t];
        float s1 = red[2 * t + 1] + red[256 + 2 * t + 1];
        bf16x2 pk; pk[0] = f2bf(s0); pk[1] = f2bf(s1);
        ((bf16x2*)(hib + (size_t)col * CC))[t] = pk;
    }
}

// ---------------------------------------------------------------- BT GEMM (shared core)
static __device__ __forceinline__ void gemm_core(
        const bf16* __restrict__ A, const bf16* __restrict__ W,
        const float* __restrict__ bias,
        float* __restrict__ outF, bf16* __restrict__ outB,
        int M, int N, int K, bf16 (*Alds)[72], bf16 (*Wlds)[72]) {
    const int tid  = threadIdx.x;
    const int wave = tid >> 6;
    const int lane = tid & 63;
    const int quad = lane >> 4;
    const int l15  = lane & 15;
    const int m0 = blockIdx.x * 128;
    const int n0 = blockIdx.y * 64;

    f32x4 acc[2][4];
    #pragma unroll
    for (int mt = 0; mt < 2; mt++)
        #pragma unroll
        for (int nt = 0; nt < 4; nt++)
            acc[mt][nt] = (f32x4){0.f, 0.f, 0.f, 0.f};

    for (int k0 = 0; k0 < K; k0 += 64) {
        #pragma unroll
        for (int i = 0; i < 4; i++) {
            int u = tid + i * 256;
            int r = u >> 3;
            int cp = u & 7;
            *reinterpret_cast<bf16x8*>(&Alds[r][cp * 8]) =
                *reinterpret_cast<const bf16x8*>(A + (size_t)(m0 + r) * K + k0 + cp * 8);
        }
        #pragma unroll
        for (int i = 0; i < 2; i++) {
            int u = tid + i * 256;
            int r = u >> 3;
            int cp = u & 7;
            *reinterpret_cast<bf16x8*>(&Wlds[r][cp * 8]) =
                *reinterpret_cast<const bf16x8*>(W + (size_t)(n0 + r) * K + k0 + cp * 8);
        }
        __syncthreads();
        #pragma unroll
        for (int c = 0; c < 2; c++) {
            bf16x8 af[2], wf[4];
            #pragma unroll
            for (int mt = 0; mt < 2; mt++)
                af[mt] = *reinterpret_cast<const bf16x8*>(&Alds[wave * 32 + mt * 16 + l15][c * 32 + quad * 8]);
            #pragma unroll
            for (int nt = 0; nt < 4; nt++)
                wf[nt] = *reinterpret_cast<const bf16x8*>(&Wlds[nt * 16 + l15][c * 32 + quad * 8]);
            #pragma unroll
            for (int mt = 0; mt < 2; mt++)
                #pragma unroll
                for (int nt = 0; nt < 4; nt++)
                    acc[mt][nt] = __builtin_amdgcn_mfma_f32_16x16x32_bf16(af[mt], wf[nt], acc[mt][nt], 0, 0, 0);
        }
        __syncthreads();
    }
    #pragma unroll
    for (int mt = 0; mt < 2; mt++)
        #pragma unroll
        for (int nt = 0; nt < 4; nt++)
            #pragma unroll
            for (int r = 0; r < 4; r++) {
                int m = m0 + wave * 32 + mt * 16 + quad * 4 + r;
                int n = n0 + nt * 16 + l15;
                float v = acc[mt][nt][r];
                if (bias) v += bias[n];
                if (outF) outF[(size_t)m * N + n] = v;
                else      outB[(size_t)m * N + n] = f2bf(v);
            }
}

__global__ __launch_bounds__(256) void gemm_bt(
        const bf16* __restrict__ A, const bf16* __restrict__ W,
        const float* __restrict__ bias,
        float* __restrict__ outF, bf16* __restrict__ outB,
        int M, int N, int K) {
    __shared__ bf16 Alds[128][72];
    __shared__ bf16 Wlds[64][72];
    gemm_core(A, W, bias, outF, outB, M, N, K, Alds, Wlds);
}

// two independent [8192,256]x[256,256] GEMMs in one launch (z picks operand set)
__global__ __launch_bounds__(256) void gemm_dual(
        const bf16* __restrict__ A0, const bf16* __restrict__ W0,
        const float* __restrict__ b0, float* __restrict__ o0,
        const bf16* __restrict__ A1, const bf16* __restrict__ W1,
        float* __restrict__ o1) {
    __shared__ bf16 Alds[128][72];
    __shared__ bf16 Wlds[64][72];
    if (blockIdx.z == 0) gemm_core(A0, W0, b0, o0, nullptr, NN, 256, 256, Alds, Wlds);
    else                 gemm_core(A1, W1, nullptr, o1, nullptr, NN, 256, 256, Alds, Wlds);
}

// ---------------------------------------------------------------- flash attention v9
// = v8 with the lpart head-indexing bug fixed: l is per-(half, head, q).
// q-split (32 q/block) halves the accumulator footprint -> 4 waves/SIMD;
// block-level key-half split keeps K/V L2 traffic at 1 GB. m = 0 softmax.
__global__ __launch_bounds__(256, 4) void flash_attn9(const bf16* __restrict__ qkv,
                                                      const bf16* __restrict__ Kpk,
                                                      const bf16* __restrict__ Vpk,
                                                      bf16* __restrict__ Opart,
                                                      float* __restrict__ lpart) {
    const int tid  = threadIdx.x;
    const int w    = tid >> 6;
    const int lane = tid & 63;
    const int quad = lane >> 4;
    const int l15  = lane & 15;
    const int bx = blockIdx.x;
    const int h    = bx & 3;
    const int qb   = (bx >> 2) & 255;
    const int half = bx >> 10;
    const int qbase = qb * 32;

    __shared__ bf16 Osh[4][32][68];
    __shared__ float lsh[4][32];

    // Q B-frags (n=q=l15, k=d=quad*8+j), prescaled by log2(e)/8
    const float qs = 0.180336880f;
    bf16x8 qf[2][2];
    #pragma unroll
    for (int qt = 0; qt < 2; qt++)
        #pragma unroll
        for (int c = 0; c < 2; c++) {
            bf16x8 raw = *reinterpret_cast<const bf16x8*>(
                qkv + (size_t)(qbase + qt * 16 + l15) * 768 + h * 64 + c * 32 + quad * 8);
            #pragma unroll
            for (int j = 0; j < 8; j++) qf[qt][c][j] = f2bf((float)raw[j] * qs);
        }

    const bf16* Kb = Kpk + (size_t)h * 524288 + lane * 8;
    const bf16* Vb = Vpk + (size_t)h * 524288 + lane * 8;
    const int cbase = half * 128 + w;

    f32x4 oacc[2][4];
    #pragma unroll
    for (int qt = 0; qt < 2; qt++)
        #pragma unroll
        for (int nt = 0; nt < 4; nt++) oacc[qt][nt] = (f32x4){0.f, 0.f, 0.f, 0.f};
    f32x4 lacc[2];
    #pragma unroll
    for (int qt = 0; qt < 2; qt++) lacc[qt] = (f32x4){0.f, 0.f, 0.f, 0.f};
    bf16x8 onesf;
    #pragma unroll
    for (int j = 0; j < 8; j++) onesf[j] = f2bf(1.0f);
    const f32x4 z4 = (f32x4){0.f, 0.f, 0.f, 0.f};

    for (int i = 0; i < 32; i++) {
        const int kc = cbase + i * 4;         // <= 128+3+124 = 255
        bf16x8 kf[2][2], vf[4];
        #pragma unroll
        for (int s = 0; s < 2; s++)
            #pragma unroll
            for (int c = 0; c < 2; c++)
                kf[s][c] = *reinterpret_cast<const bf16x8*>(Kb + kc * 2048 + s * 1024 + c * 512);
        #pragma unroll
        for (int nt = 0; nt < 4; nt++)
            vf[nt] = *reinterpret_cast<const bf16x8*>(Vb + kc * 2048 + nt * 512);

        f32x4 sacc[2][2];
        #pragma unroll
        for (int s = 0; s < 2; s++)
            #pragma unroll
            for (int qt = 0; qt < 2; qt++) {
                sacc[s][qt] = __builtin_amdgcn_mfma_f32_16x16x32_bf16(kf[s][0], qf[qt][0], z4, 0, 0, 0);
                sacc[s][qt] = __builtin_amdgcn_mfma_f32_16x16x32_bf16(kf[s][1], qf[qt][1], sacc[s][qt], 0, 0, 0);
            }
        #pragma unroll
        for (int qt = 0; qt < 2; qt++) {
            float e0 = __builtin_amdgcn_exp2f(sacc[0][qt][0]);
            float e1 = __builtin_amdgcn_exp2f(sacc[0][qt][1]);
            float e2 = __builtin_amdgcn_exp2f(sacc[0][qt][2]);
            float e3 = __builtin_amdgcn_exp2f(sacc[0][qt][3]);
            float e4 = __builtin_amdgcn_exp2f(sacc[1][qt][0]);
            float e5 = __builtin_amdgcn_exp2f(sacc[1][qt][1]);
            float e6 = __builtin_amdgcn_exp2f(sacc[1][qt][2]);
            float e7 = __builtin_amdgcn_exp2f(sacc[1][qt][3]);
            union { bf16x8 v; unsigned u[4]; } pu;
            pu.u[0] = pk2(e0, e1);
            pu.u[1] = pk2(e2, e3);
            pu.u[2] = pk2(e4, e5);
            pu.u[3] = pk2(e6, e7);
            #pragma unroll
            for (int nt = 0; nt < 4; nt++)
                oacc[qt][nt] = __builtin_amdgcn_mfma_f32_16x16x32_bf16(pu.v, vf[nt], oacc[qt][nt], 0, 0, 0);
            lacc[qt] = __builtin_amdgcn_mfma_f32_16x16x32_bf16(pu.v, onesf, lacc[qt], 0, 0, 0);
        }
    }

    // ---- in-block 4-wave merge (plain sums; m == 0)
    #pragma unroll
    for (int qt = 0; qt < 2; qt++)
        #pragma unroll
        for (int nt = 0; nt < 4; nt++)
            #pragma unroll
            for (int r = 0; r < 4; r++)
                Osh[w][qt * 16 + quad * 4 + r][nt * 16 + l15] = f2bf(oacc[qt][nt][r]);
    if (l15 == 0) {
        #pragma unroll
        for (int qt = 0; qt < 2; qt++)
            #pragma unroll
            for (int r = 0; r < 4; r++)
                lsh[w][qt * 16 + quad * 4 + r] = lacc[qt][r];
    }
    __syncthreads();

    const int q32 = tid >> 3;            // 0..31
    const int dg = tid & 7;              // 8 channels each
    const int d0 = dg * 8;
    float acc[8];
    #pragma unroll
    for (int i = 0; i < 8; i++) acc[i] = 0.f;
    #pragma unroll
    for (int v = 0; v < 4; v++) {
        bf16x8 ov = *reinterpret_cast<const bf16x8*>(&Osh[v][q32][d0]);
        #pragma unroll
        for (int i = 0; i < 8; i++) acc[i] += (float)ov[i];
    }
    bf16x8 ob;
    #pragma unroll
    for (int i = 0; i < 8; i++) ob[i] = f2bf(acc[i]);
    *reinterpret_cast<bf16x8*>(Opart + (size_t)half * 2097152
                               + (size_t)(qbase + q32) * 256 + h * 64 + d0) = ob;
    if (dg == 0)
        lpart[((half << 2) + h) * 8192 + qbase + q32] =
            lsh[0][q32] + lsh[1][q32] + lsh[2][q32] + lsh[3][q32];
}

// attnO = (O0+O1)/(l0+l1); l indexed per (half, head, q). grid 512.
__global__ __launch_bounds__(256) void attn_merge(const bf16* __restrict__ Opart,
                                                  const float* __restrict__ lpart,
                                                  bf16* __restrict__ attnO) {
    const int t = threadIdx.x;
    const int q = blockIdx.x * 16 + (t >> 4);
    const int c0 = (t & 15) * 16;
    const int h = c0 >> 6;
    const float linv = 1.f / (lpart[h * 8192 + q] + lpart[(4 + h) * 8192 + q]);
    const bf16* p0 = Opart + (size_t)q * 256 + c0;
    const bf16* p1 = p0 + 2097152;
    bf16x8 a0 = *reinterpret_cast<const bf16x8*>(p0);
    bf16x8 a1 = *reinterpret_cast<const bf16x8*>(p0 + 8);
    bf16x8 b0 = *reinterpret_cast<const bf16x8*>(p1);
    bf16x8 b1 = *reinterpret_cast<const bf16x8*>(p1 + 8);
    bf16x8 o0, o1;
    #pragma unroll
    for (int i = 0; i < 8; i++) {
        o0[i] = f2bf(((float)a0[i] + (float)b0[i]) * linv);
        o1[i] = f2bf(((float)a1[i] + (float)b1[i]) * linv);
    }
    bf16* dst = attnO + (size_t)q * CC + c0;
    *reinterpret_cast<bf16x8*>(dst) = o0;
    *reinterpret_cast<bf16x8*>(dst + 8) = o1;
}

// ---------------------------------------------------------------- LN + combine (wave/row)
__global__ __launch_bounds__(256) void ln_combine2(
        const float* __restrict__ x, const float* __restrict__ aproj,
        const float* __restrict__ local, const float* __restrict__ g,
        const float* __restrict__ b, const float* __restrict__ alpha_p,
        bf16* __restrict__ comb) {
    const int row = blockIdx.x * 4 + (threadIdx.x >> 6);
    const int lane = threadIdx.x & 63;
    const f32x4 xv = ((const f32x4*)(x + (size_t)row * CC))[lane];
    const f32x4 av = ((const f32x4*)(aproj + (size_t)row * CC))[lane];
    f32x4 v = xv + av;
    float s = v[0] + v[1] + v[2] + v[3];
    #pragma unroll
    for (int off = 1; off < 64; off <<= 1) s += __shfl_xor(s, off);
    float mu = s * (1.f / CC);
    f32x4 d = v - mu;
    float ss = d[0] * d[0] + d[1] * d[1] + d[2] * d[2] + d[3] * d[3];
    #pragma unroll
    for (int off = 1; off < 64; off <<= 1) ss += __shfl_xor(ss, off);
    float rstd = rsqrtf(ss * (1.f / CC) + 1e-5f);
    const f32x4 gv = ((const f32x4*)g)[lane];
    const f32x4 bv = ((const f32x4*)b)[lane];
    const f32x4 lv = ((const f32x4*)(local + (size_t)row * CC))[lane];
    float wgt = 1.f / (1.f + __expf(-alpha_p[0]));
    bf16x4 o;
    #pragma unroll
    for (int i = 0; i < 4; i++)
        o[i] = f2bf(wgt * lv[i] + (1.f - wgt) * (d[i] * rstd * gv[i] + bv[i]));
    ((bf16x4*)(comb + (size_t)row * CC))[lane] = o;
}

// ---------------------------------------------------------------- launch
extern "C" void kernel_launch(void* const* d_in, const int* in_sizes, int n_in,
                              void* d_out, int out_size, void* d_ws, size_t ws_size,
                              hipStream_t stream) {
    (void)in_sizes; (void)n_in; (void)out_size; (void)ws_size;
    const float* x    = (const float*)d_in[0];
    const int*   adj  = (const int*)d_in[1];
    const float* wloc = (const float*)d_in[2];
    const float* ipw  = (const float*)d_in[3];
    const float* ipb  = (const float*)d_in[4];
    const float* opw  = (const float*)d_in[5];
    const float* opb  = (const float*)d_in[6];
    const float* lng  = (const float*)d_in[7];
    const float* lnb  = (const float*)d_in[8];
    const float* alp  = (const float*)d_in[9];
    const float* fcw  = (const float*)d_in[10];
    const float* fcb  = (const float*)d_in[11];
    float* out = (float*)d_out;

    char* p = (char*)d_ws;
    int*   ideg   = (int*)p;    p += (size_t)NN * 4;
    int*   off    = (int*)p;    p += (size_t)(NN + 1) * 4;
    int*   cursor = (int*)p;    p += (size_t)NN * 4;
    float* rs     = (float*)p;  p += (size_t)NN * 4;
    int*   csr    = (int*)p;    p += (size_t)EE * 4;
    bf16* xb    = (bf16*)p;   p += (size_t)NN * CC * 2;
    bf16* hib   = (bf16*)p;   p += (size_t)NN * CC * 2;
    bf16* ipwb  = (bf16*)p;   p += (size_t)768 * 256 * 2;
    bf16* wlTb  = (bf16*)p;   p += (size_t)256 * 256 * 2;
    bf16* opwb  = (bf16*)p;   p += (size_t)256 * 256 * 2;
    bf16* fcwb  = (bf16*)p;   p += (size_t)256 * 256 * 2;
    bf16* qkvb  = (bf16*)p;   p += (size_t)NN * 768 * 2;
    bf16* Kpk   = (bf16*)p;   p += (size_t)HH * 512 * 2 * 512 * 2;
    bf16* Vpk   = (bf16*)p;   p += (size_t)HH * 256 * 4 * 512 * 2;
    bf16* aOb   = (bf16*)p;   p += (size_t)NN * CC * 2;
    float* aprj = (float*)p;  p += (size_t)NN * CC * 4;
    float* locl = (float*)p;  p += (size_t)NN * CC * 4;
    bf16* comb  = (bf16*)p;   p += (size_t)NN * CC * 2;
    // flash partials alias later-written buffers (disjoint lifetimes):
    bf16*  Opart = (bf16*)aprj;     // 8 MB: flash9 -> attn_merge, then aprj gemm overwrites
    float* lpart = (float*)locl;    // 256 KB: same pattern

    hipMemsetAsync(ideg, 0, (size_t)NN * 4, stream);

    prep_all<<<4608, 256, 0, stream>>>(x, xb, ipw, opw, fcw, wloc, ipwb, opwb, fcwb, wlTb, adj, ideg);
    scan_offsets<<<1, 256, 0, stream>>>(ideg, off, cursor, rs);
    fill_csr<<<EE / 256, 256, 0, stream>>>(adj, cursor, csr);
    gcn_gather2<<<NN, 256, 0, stream>>>(xb, csr, off, rs, hib);

    gemm_bt<<<dim3(NN / 128, 768 / 64), 256, 0, stream>>>(xb, ipwb, ipb, nullptr, qkvb, NN, 768, 256);
    build_kv<<<dim3(NN / 64, HH), 256, 0, stream>>>(qkvb, Kpk, Vpk);
    flash_attn9<<<2048, 256, 0, stream>>>(qkvb, Kpk, Vpk, Opart, lpart);
    attn_merge<<<512, 256, 0, stream>>>(Opart, lpart, aOb);
    gemm_dual<<<dim3(NN / 128, 4, 2), 256, 0, stream>>>(aOb, opwb, opb, aprj, hib, wlTb, locl);
    ln_combine2<<<NN / 4, 256, 0, stream>>>(x, aprj, locl, lng, lnb, alp, comb);
    gemm_bt<<<dim3(NN / 128, 256 / 64), 256, 0, stream>>>(comb, fcwb, fcb, out, nullptr, NN, 256, 256);
}

// Round 10
// 282.988 us; speedup vs baseline: 1.0954x; 1.0778x over previous
//
#include <hip/hip_runtime.h>
#include <hip/hip_bf16.h>
#include <math.h>

#define NN   8192
#define EE   262144
#define CC   256
#define HH   4

typedef __bf16 bf16;
typedef __bf16 bf16x8 __attribute__((ext_vector_type(8)));
typedef __bf16 bf16x4 __attribute__((ext_vector_type(4)));
typedef __bf16 bf16x2 __attribute__((ext_vector_type(2)));
typedef float  f32x4  __attribute__((ext_vector_type(4)));

static __device__ __forceinline__ bf16 f2bf(float f) { return (bf16)f; }

// packed f32x2 -> bf16x2 in one dword (v_cvt_pk_bf16_f32)
static __device__ __forceinline__ unsigned pk2(float a, float b) {
    __hip_bfloat162 h = __float22bfloat162_rn(float2{a, b});
    return *reinterpret_cast<unsigned*>(&h);
}

// ---------------------------------------------------------------- fused prep
__global__ void prep_all(const float* __restrict__ x, bf16* __restrict__ xb,
                         const float* __restrict__ ipw, const float* __restrict__ opw,
                         const float* __restrict__ fcw, const float* __restrict__ wloc,
                         bf16* __restrict__ ipwb, bf16* __restrict__ opwb,
                         bf16* __restrict__ fcwb, bf16* __restrict__ wlTb,
                         const int* __restrict__ adj, int* __restrict__ ideg) {
    int b = blockIdx.x, t = threadIdx.x;
    if (b < 2048) {
        for (int i = b * 256 + t; i < NN * CC; i += 2048 * 256) xb[i] = f2bf(x[i]);
    } else if (b < 2816) { int i = (b - 2048) * 256 + t; ipwb[i] = f2bf(ipw[i]); }
    else if (b < 3072)   { int i = (b - 2816) * 256 + t; opwb[i] = f2bf(opw[i]); }
    else if (b < 3328)   { int i = (b - 3072) * 256 + t; fcwb[i] = f2bf(fcw[i]); }
    else if (b < 3584)   { int n = b - 3328;             wlTb[n * 256 + t] = f2bf(wloc[t * 256 + n]); }
    else {
        int e = (b - 3584) * 256 + t;
        if (e < EE) atomicAdd(&ideg[adj[EE + e]], 1);
    }
}

// ---------------------------------------------------------------- K/V fragment prepack (fused)
__global__ __launch_bounds__(256) void build_kv(const bf16* __restrict__ qkv,
                                                bf16* __restrict__ Kpk,
                                                bf16* __restrict__ Vpk) {
    __shared__ bf16 tl[64][72];
    const int bx = blockIdx.x;     // 64-key tile
    const int h  = blockIdx.y;
    const int tid = threadIdx.x;
    // ---- K
    #pragma unroll
    for (int i = 0; i < 2; i++) {
        int u = tid + i * 256;
        int key = u >> 3, g = u & 7;
        *reinterpret_cast<bf16x8*>(&tl[key][g * 8]) =
            *reinterpret_cast<const bf16x8*>(qkv + (size_t)(bx * 64 + key) * 768 + 256 + h * 64 + g * 8);
    }
    __syncthreads();
    #pragma unroll
    for (int i = 0; i < 2; i++) {
        int ee = tid + i * 256;
        int l15 = ee & 15, quad = (ee >> 4) & 3, c = (ee >> 6) & 1, ktl = ee >> 7;
        int key_local = (ktl >> 1) * 32 + (l15 >> 2) * 8 + (ktl & 1) * 4 + (l15 & 3);
        bf16x8 v = *reinterpret_cast<const bf16x8*>(&tl[key_local][c * 32 + quad * 8]);
        *reinterpret_cast<bf16x8*>(Kpk + ((size_t)((h * 512 + bx * 4 + ktl) * 2 + c)) * 512
                                       + (quad * 16 + l15) * 8) = v;
    }
    __syncthreads();
    // ---- V
    #pragma unroll
    for (int i = 0; i < 2; i++) {
        int u = tid + i * 256;
        int key = u >> 3, g = u & 7;
        *reinterpret_cast<bf16x8*>(&tl[key][g * 8]) =
            *reinterpret_cast<const bf16x8*>(qkv + (size_t)(bx * 64 + key) * 768 + 512 + h * 64 + g * 8);
    }
    __syncthreads();
    #pragma unroll
    for (int i = 0; i < 2; i++) {
        int ee = tid + i * 256;
        int l15 = ee & 15, quad = (ee >> 4) & 3, nt = (ee >> 6) & 3, kcl = ee >> 8;
        bf16x8 v;
        #pragma unroll
        for (int j = 0; j < 8; j++) v[j] = tl[kcl * 32 + quad * 8 + j][nt * 16 + l15];
        *reinterpret_cast<bf16x8*>(Vpk + ((size_t)((h * 256 + bx * 2 + kcl) * 4 + nt)) * 512
                                       + (quad * 16 + l15) * 8) = v;
    }
}

// ---------------------------------------------------------------- GCN conv (CSR gather)
__global__ __launch_bounds__(256) void scan_offsets(const int* __restrict__ ideg,
        int* __restrict__ off, int* __restrict__ cursor, float* __restrict__ rs) {
    __shared__ int ps[256];
    const int tid = threadIdx.x;
    const int base = tid * 32;
    int loc[32];
    int s = 0;
    #pragma unroll
    for (int i = 0; i < 32; i++) { loc[i] = s; s += ideg[base + i]; }
    ps[tid] = s;
    __syncthreads();
    for (int d = 1; d < 256; d <<= 1) {
        int v = (tid >= d) ? ps[tid - d] : 0;
        __syncthreads();
        ps[tid] += v;
        __syncthreads();
    }
    int excl = ps[tid] - s;
    #pragma unroll
    for (int i = 0; i < 32; i++) {
        int o = excl + loc[i];
        off[base + i] = o;
        cursor[base + i] = o;
        int dg = ideg[base + i];
        rs[base + i] = dg > 0 ? rsqrtf((float)dg) : 0.f;
    }
    if (tid == 255) off[8192] = excl + s;
}

__global__ void fill_csr(const int* __restrict__ adj, int* __restrict__ cursor,
                         int* __restrict__ csr) {
    int e = blockIdx.x * 256 + threadIdx.x;
    if (e < EE) {
        int col = adj[EE + e];
        int pos = atomicAdd(&cursor[col], 1);
        csr[pos] = adj[e];
    }
}

__global__ __launch_bounds__(256) void gcn_gather2(const bf16* __restrict__ xb,
        const int* __restrict__ csr, const int* __restrict__ off,
        const float* __restrict__ rs, bf16* __restrict__ hib) {
    const int col = blockIdx.x;
    const int t = threadIdx.x;
    const int half = t >> 7;
    const int j = t & 127;
    const int o = off[col];
    const int cnt = off[col + 1] - o;
    const float rsc = rs[col];
    float a0 = 0.f, a1 = 0.f;
    for (int e = half; e < cnt; e += 2) {
        int r = csr[o + e];
        float v = rsc * rs[r];
        unsigned u = ((const unsigned*)(xb + (size_t)r * CC))[j];
        a0 += __uint_as_float(u << 16) * v;
        a1 += __uint_as_float(u & 0xffff0000u) * v;
    }
    __shared__ float red[512];
    red[half * 256 + 2 * j]     = a0;
    red[half * 256 + 2 * j + 1] = a1;
    __syncthreads();
    if (t < 128) {
        float s0 = red[2 * t]     + red[256 + 2 * t];
        float s1 = red[2 * t + 1] + red[256 + 2 * t + 1];
        bf16x2 pk; pk[0] = f2bf(s0); pk[1] = f2bf(s1);
        ((bf16x2*)(hib + (size_t)col * CC))[t] = pk;
    }
}

// ---------------------------------------------------------------- BT GEMM (shared core)
static __device__ __forceinline__ void gemm_core(
        const bf16* __restrict__ A, const bf16* __restrict__ W,
        const float* __restrict__ bias,
        float* __restrict__ outF, bf16* __restrict__ outB,
        int M, int N, int K, bf16 (*Alds)[72], bf16 (*Wlds)[72]) {
    const int tid  = threadIdx.x;
    const int wave = tid >> 6;
    const int lane = tid & 63;
    const int quad = lane >> 4;
    const int l15  = lane & 15;
    const int m0 = blockIdx.x * 128;
    const int n0 = blockIdx.y * 64;

    f32x4 acc[2][4];
    #pragma unroll
    for (int mt = 0; mt < 2; mt++)
        #pragma unroll
        for (int nt = 0; nt < 4; nt++)
            acc[mt][nt] = (f32x4){0.f, 0.f, 0.f, 0.f};

    for (int k0 = 0; k0 < K; k0 += 64) {
        #pragma unroll
        for (int i = 0; i < 4; i++) {
            int u = tid + i * 256;
            int r = u >> 3;
            int cp = u & 7;
            *reinterpret_cast<bf16x8*>(&Alds[r][cp * 8]) =
                *reinterpret_cast<const bf16x8*>(A + (size_t)(m0 + r) * K + k0 + cp * 8);
        }
        #pragma unroll
        for (int i = 0; i < 2; i++) {
            int u = tid + i * 256;
            int r = u >> 3;
            int cp = u & 7;
            *reinterpret_cast<bf16x8*>(&Wlds[r][cp * 8]) =
                *reinterpret_cast<const bf16x8*>(W + (size_t)(n0 + r) * K + k0 + cp * 8);
        }
        __syncthreads();
        #pragma unroll
        for (int c = 0; c < 2; c++) {
            bf16x8 af[2], wf[4];
            #pragma unroll
            for (int mt = 0; mt < 2; mt++)
                af[mt] = *reinterpret_cast<const bf16x8*>(&Alds[wave * 32 + mt * 16 + l15][c * 32 + quad * 8]);
            #pragma unroll
            for (int nt = 0; nt < 4; nt++)
                wf[nt] = *reinterpret_cast<const bf16x8*>(&Wlds[nt * 16 + l15][c * 32 + quad * 8]);
            #pragma unroll
            for (int mt = 0; mt < 2; mt++)
                #pragma unroll
                for (int nt = 0; nt < 4; nt++)
                    acc[mt][nt] = __builtin_amdgcn_mfma_f32_16x16x32_bf16(af[mt], wf[nt], acc[mt][nt], 0, 0, 0);
        }
        __syncthreads();
    }
    #pragma unroll
    for (int mt = 0; mt < 2; mt++)
        #pragma unroll
        for (int nt = 0; nt < 4; nt++)
            #pragma unroll
            for (int r = 0; r < 4; r++) {
                int m = m0 + wave * 32 + mt * 16 + quad * 4 + r;
                int n = n0 + nt * 16 + l15;
                float v = acc[mt][nt][r];
                if (bias) v += bias[n];
                if (outF) outF[(size_t)m * N + n] = v;
                else      outB[(size_t)m * N + n] = f2bf(v);
            }
}

__global__ __launch_bounds__(256) void gemm_bt(
        const bf16* __restrict__ A, const bf16* __restrict__ W,
        const float* __restrict__ bias,
        float* __restrict__ outF, bf16* __restrict__ outB,
        int M, int N, int K) {
    __shared__ bf16 Alds[128][72];
    __shared__ bf16 Wlds[64][72];
    gemm_core(A, W, bias, outF, outB, M, N, K, Alds, Wlds);
}

// two independent [8192,256]x[256,256] GEMMs in one launch (z picks operand set)
__global__ __launch_bounds__(256) void gemm_dual(
        const bf16* __restrict__ A0, const bf16* __restrict__ W0,
        const float* __restrict__ b0, float* __restrict__ o0,
        const bf16* __restrict__ A1, const bf16* __restrict__ W1,
        float* __restrict__ o1) {
    __shared__ bf16 Alds[128][72];
    __shared__ bf16 Wlds[64][72];
    if (blockIdx.z == 0) gemm_core(A0, W0, b0, o0, nullptr, NN, 256, 256, Alds, Wlds);
    else                 gemm_core(A1, W1, nullptr, o1, nullptr, NN, 256, 256, Alds, Wlds);
}

// ---------------------------------------------------------------- flash attention v10
// 512-thread blocks, grid 256 (1 block/CU): block = (head, 128 q) x ALL keys.
// Two q-groups of 4 waves; within a group keys split 4-way (64 chunk-iters per
// wave, v6's exact per-wave code: m = 0 softmax, ping-pong double buffer, l via
// P*(ones) MFMA). Unique K/V reads: 256 x 2 MB = 0.5 GB (half v6, quarter v9);
// paired-group re-reads hit L1. Block covers all keys -> writes normalized
// attnO directly (no partials, no merge kernel). 8-way merge in 72 KB LDS.
__global__ __launch_bounds__(512, 2) void flash_attn10(const bf16* __restrict__ qkv,
                                                       const bf16* __restrict__ Kpk,
                                                       const bf16* __restrict__ Vpk,
                                                       bf16* __restrict__ attnO) {
    const int tid  = threadIdx.x;
    const int w    = tid >> 6;           // 0..7
    const int g    = w >> 2;             // q-group
    const int k4   = w & 3;              // key-split lane within group
    const int lane = tid & 63;
    const int quad = lane >> 4;
    const int l15  = lane & 15;
    const int bx = blockIdx.x;
    const int h  = bx & 3;
    const int qb = bx >> 2;              // 0..63
    const int qbase = qb * 128 + g * 64;

    __shared__ bf16 Osh[8][64][68];
    __shared__ float lsh[8][64];

    // Q B-frags (n=q=l15, k=d=quad*8+j), prescaled by log2(e)/8
    const float qs = 0.180336880f;
    bf16x8 qf[4][2];
    #pragma unroll
    for (int qt = 0; qt < 4; qt++)
        #pragma unroll
        for (int c = 0; c < 2; c++) {
            bf16x8 raw = *reinterpret_cast<const bf16x8*>(
                qkv + (size_t)(qbase + qt * 16 + l15) * 768 + h * 64 + c * 32 + quad * 8);
            #pragma unroll
            for (int j = 0; j < 8; j++) qf[qt][c][j] = f2bf((float)raw[j] * qs);
        }

    const bf16* Kb = Kpk + (size_t)h * 524288 + lane * 8;
    const bf16* Vb = Vpk + (size_t)h * 524288 + lane * 8;

    f32x4 oacc[4][4];
    #pragma unroll
    for (int qt = 0; qt < 4; qt++)
        #pragma unroll
        for (int nt = 0; nt < 4; nt++) oacc[qt][nt] = (f32x4){0.f, 0.f, 0.f, 0.f};
    f32x4 lacc[4];
    #pragma unroll
    for (int qt = 0; qt < 4; qt++) lacc[qt] = (f32x4){0.f, 0.f, 0.f, 0.f};
    bf16x8 onesf;
    #pragma unroll
    for (int j = 0; j < 8; j++) onesf[j] = f2bf(1.0f);
    const f32x4 z4 = (f32x4){0.f, 0.f, 0.f, 0.f};

    bf16x8 kfA[2][2], vfA[4], kfB[2][2], vfB[4];

    #define LOADKV(kc, kf, vf)                                                          \
        {                                                                               \
            _Pragma("unroll")                                                           \
            for (int s = 0; s < 2; s++)                                                 \
                _Pragma("unroll")                                                       \
                for (int c = 0; c < 2; c++)                                             \
                    kf[s][c] = *reinterpret_cast<const bf16x8*>(Kb + (kc) * 2048 + s * 1024 + c * 512); \
            _Pragma("unroll")                                                           \
            for (int nt = 0; nt < 4; nt++)                                              \
                vf[nt] = *reinterpret_cast<const bf16x8*>(Vb + (kc) * 2048 + nt * 512); \
        }

    #define COMPUTE(kf, vf)                                                             \
        {                                                                               \
            f32x4 sacc[2][4];                                                           \
            _Pragma("unroll")                                                           \
            for (int s = 0; s < 2; s++)                                                 \
                _Pragma("unroll")                                                       \
                for (int qt = 0; qt < 4; qt++) {                                        \
                    sacc[s][qt] = __builtin_amdgcn_mfma_f32_16x16x32_bf16(kf[s][0], qf[qt][0], z4, 0, 0, 0); \
                    sacc[s][qt] = __builtin_amdgcn_mfma_f32_16x16x32_bf16(kf[s][1], qf[qt][1], sacc[s][qt], 0, 0, 0); \
                }                                                                       \
            _Pragma("unroll")                                                           \
            for (int qt = 0; qt < 4; qt++) {                                            \
                float e0 = __builtin_amdgcn_exp2f(sacc[0][qt][0]);                      \
                float e1 = __builtin_amdgcn_exp2f(sacc[0][qt][1]);                      \
                float e2 = __builtin_amdgcn_exp2f(sacc[0][qt][2]);                      \
                float e3 = __builtin_amdgcn_exp2f(sacc[0][qt][3]);                      \
                float e4 = __builtin_amdgcn_exp2f(sacc[1][qt][0]);                      \
                float e5 = __builtin_amdgcn_exp2f(sacc[1][qt][1]);                      \
                float e6 = __builtin_amdgcn_exp2f(sacc[1][qt][2]);                      \
                float e7 = __builtin_amdgcn_exp2f(sacc[1][qt][3]);                      \
                union { bf16x8 v; unsigned u[4]; } pu;                                  \
                pu.u[0] = pk2(e0, e1);                                                  \
                pu.u[1] = pk2(e2, e3);                                                  \
                pu.u[2] = pk2(e4, e5);                                                  \
                pu.u[3] = pk2(e6, e7);                                                  \
                _Pragma("unroll")                                                       \
                for (int nt = 0; nt < 4; nt++)                                          \
                    oacc[qt][nt] = __builtin_amdgcn_mfma_f32_16x16x32_bf16(pu.v, vf[nt], oacc[qt][nt], 0, 0, 0); \
                lacc[qt] = __builtin_amdgcn_mfma_f32_16x16x32_bf16(pu.v, onesf, lacc[qt], 0, 0, 0); \
            }                                                                           \
        }

    LOADKV(k4, kfA, vfA);
    for (int it = 0; it < 64; it += 2) {
        const int kB = k4 + (it + 1) * 4;             // <= 3 + 63*4 = 255: in range
        LOADKV(kB, kfB, vfB);
        COMPUTE(kfA, vfA);
        int kA2 = k4 + (it + 2) * 4;
        if (kA2 > 255) kA2 = k4;                      // last prefetch wasted, harmless
        LOADKV(kA2, kfA, vfA);
        COMPUTE(kfB, vfB);
    }
    #undef LOADKV
    #undef COMPUTE

    // ---- 8-way merge (plain sums; m == 0 everywhere)
    #pragma unroll
    for (int qt = 0; qt < 4; qt++)
        #pragma unroll
        for (int nt = 0; nt < 4; nt++)
            #pragma unroll
            for (int r = 0; r < 4; r++)
                Osh[w][qt * 16 + quad * 4 + r][nt * 16 + l15] = f2bf(oacc[qt][nt][r]);
    if (l15 == 0) {
        #pragma unroll
        for (int qt = 0; qt < 4; qt++)
            #pragma unroll
            for (int r = 0; r < 4; r++)
                lsh[w][qt * 16 + quad * 4 + r] = lacc[qt][r];
    }
    __syncthreads();

    const int q7 = tid >> 2;             // 0..127
    const int gg = q7 >> 6;
    const int ql = q7 & 63;
    const int ds = (tid & 3) * 16;
    const int wb = gg * 4;
    float lsum = lsh[wb][ql] + lsh[wb + 1][ql] + lsh[wb + 2][ql] + lsh[wb + 3][ql];
    float linv = 1.f / lsum;
    float acc[16];
    #pragma unroll
    for (int i = 0; i < 16; i++) acc[i] = 0.f;
    #pragma unroll
    for (int v = 0; v < 4; v++) {
        bf16x8 o0 = *reinterpret_cast<const bf16x8*>(&Osh[wb + v][ql][ds]);
        bf16x8 o1 = *reinterpret_cast<const bf16x8*>(&Osh[wb + v][ql][ds + 8]);
        #pragma unroll
        for (int i = 0; i < 8; i++) { acc[i] += (float)o0[i]; acc[8 + i] += (float)o1[i]; }
    }
    bf16x8 ob0, ob1;
    #pragma unroll
    for (int i = 0; i < 8; i++) {
        ob0[i] = f2bf(acc[i] * linv);
        ob1[i] = f2bf(acc[8 + i] * linv);
    }
    bf16* dst = attnO + (size_t)(qb * 128 + q7) * CC + h * 64 + ds;
    *reinterpret_cast<bf16x8*>(dst) = ob0;
    *reinterpret_cast<bf16x8*>(dst + 8) = ob1;
}

// ---------------------------------------------------------------- LN + combine (wave/row)
__global__ __launch_bounds__(256) void ln_combine2(
        const float* __restrict__ x, const float* __restrict__ aproj,
        const float* __restrict__ local, const float* __restrict__ g,
        const float* __restrict__ b, const float* __restrict__ alpha_p,
        bf16* __restrict__ comb) {
    const int row = blockIdx.x * 4 + (threadIdx.x >> 6);
    const int lane = threadIdx.x & 63;
    const f32x4 xv = ((const f32x4*)(x + (size_t)row * CC))[lane];
    const f32x4 av = ((const f32x4*)(aproj + (size_t)row * CC))[lane];
    f32x4 v = xv + av;
    float s = v[0] + v[1] + v[2] + v[3];
    #pragma unroll
    for (int off = 1; off < 64; off <<= 1) s += __shfl_xor(s, off);
    float mu = s * (1.f / CC);
    f32x4 d = v - mu;
    float ss = d[0] * d[0] + d[1] * d[1] + d[2] * d[2] + d[3] * d[3];
    #pragma unroll
    for (int off = 1; off < 64; off <<= 1) ss += __shfl_xor(ss, off);
    float rstd = rsqrtf(ss * (1.f / CC) + 1e-5f);
    const f32x4 gv = ((const f32x4*)g)[lane];
    const f32x4 bv = ((const f32x4*)b)[lane];
    const f32x4 lv = ((const f32x4*)(local + (size_t)row * CC))[lane];
    float wgt = 1.f / (1.f + __expf(-alpha_p[0]));
    bf16x4 o;
    #pragma unroll
    for (int i = 0; i < 4; i++)
        o[i] = f2bf(wgt * lv[i] + (1.f - wgt) * (d[i] * rstd * gv[i] + bv[i]));
    ((bf16x4*)(comb + (size_t)row * CC))[lane] = o;
}

// ---------------------------------------------------------------- launch
extern "C" void kernel_launch(void* const* d_in, const int* in_sizes, int n_in,
                              void* d_out, int out_size, void* d_ws, size_t ws_size,
                              hipStream_t stream) {
    (void)in_sizes; (void)n_in; (void)out_size; (void)ws_size;
    const float* x    = (const float*)d_in[0];
    const int*   adj  = (const int*)d_in[1];
    const float* wloc = (const float*)d_in[2];
    const float* ipw  = (const float*)d_in[3];
    const float* ipb  = (const float*)d_in[4];
    const float* opw  = (const float*)d_in[5];
    const float* opb  = (const float*)d_in[6];
    const float* lng  = (const float*)d_in[7];
    const float* lnb  = (const float*)d_in[8];
    const float* alp  = (const float*)d_in[9];
    const float* fcw  = (const float*)d_in[10];
    const float* fcb  = (const float*)d_in[11];
    float* out = (float*)d_out;

    char* p = (char*)d_ws;
    int*   ideg   = (int*)p;    p += (size_t)NN * 4;
    int*   off    = (int*)p;    p += (size_t)(NN + 1) * 4;
    int*   cursor = (int*)p;    p += (size_t)NN * 4;
    float* rs     = (float*)p;  p += (size_t)NN * 4;
    int*   csr    = (int*)p;    p += (size_t)EE * 4;
    bf16* xb    = (bf16*)p;   p += (size_t)NN * CC * 2;
    bf16* hib   = (bf16*)p;   p += (size_t)NN * CC * 2;
    bf16* ipwb  = (bf16*)p;   p += (size_t)768 * 256 * 2;
    bf16* wlTb  = (bf16*)p;   p += (size_t)256 * 256 * 2;
    bf16* opwb  = (bf16*)p;   p += (size_t)256 * 256 * 2;
    bf16* fcwb  = (bf16*)p;   p += (size_t)256 * 256 * 2;
    bf16* qkvb  = (bf16*)p;   p += (size_t)NN * 768 * 2;
    bf16* Kpk   = (bf16*)p;   p += (size_t)HH * 512 * 2 * 512 * 2;
    bf16* Vpk   = (bf16*)p;   p += (size_t)HH * 256 * 4 * 512 * 2;
    bf16* aOb   = (bf16*)p;   p += (size_t)NN * CC * 2;
    float* aprj = (float*)p;  p += (size_t)NN * CC * 4;
    float* locl = (float*)p;  p += (size_t)NN * CC * 4;
    bf16* comb  = (bf16*)p;   p += (size_t)NN * CC * 2;

    hipMemsetAsync(ideg, 0, (size_t)NN * 4, stream);

    prep_all<<<4608, 256, 0, stream>>>(x, xb, ipw, opw, fcw, wloc, ipwb, opwb, fcwb, wlTb, adj, ideg);
    scan_offsets<<<1, 256, 0, stream>>>(ideg, off, cursor, rs);
    fill_csr<<<EE / 256, 256, 0, stream>>>(adj, cursor, csr);
    gcn_gather2<<<NN, 256, 0, stream>>>(xb, csr, off, rs, hib);

    gemm_bt<<<dim3(NN / 128, 768 / 64), 256, 0, stream>>>(xb, ipwb, ipb, nullptr, qkvb, NN, 768, 256);
    build_kv<<<dim3(NN / 64, HH), 256, 0, stream>>>(qkvb, Kpk, Vpk);
    flash_attn10<<<256, 512, 0, stream>>>(qkvb, Kpk, Vpk, aOb);
    gemm_dual<<<dim3(NN / 128, 4, 2), 256, 0, stream>>>(aOb, opwb, opb, aprj, hib, wlTb, locl);
    ln_combine2<<<NN / 4, 256, 0, stream>>>(x, aprj, locl, lng, lnb, alp, comb);
    gemm_bt<<<dim3(NN / 128, 256 / 64), 256, 0, stream>>>(comb, fcwb, fcb, out, nullptr, NN, 256, 256);
}

// Round 11
// 276.598 us; speedup vs baseline: 1.1207x; 1.0231x over previous
//
#include <hip/hip_runtime.h>
#include <hip/hip_bf16.h>
#include <math.h>

#define NN   8192
#define EE   262144
#define CC   256
#define HH   4

typedef __bf16 bf16;
typedef __bf16 bf16x8 __attribute__((ext_vector_type(8)));
typedef __bf16 bf16x4 __attribute__((ext_vector_type(4)));
typedef __bf16 bf16x2 __attribute__((ext_vector_type(2)));
typedef float  f32x4  __attribute__((ext_vector_type(4)));

static __device__ __forceinline__ bf16 f2bf(float f) { return (bf16)f; }

// packed f32x2 -> bf16x2 in one dword (v_cvt_pk_bf16_f32)
static __device__ __forceinline__ unsigned pk2(float a, float b) {
    __hip_bfloat162 h = __float22bfloat162_rn(float2{a, b});
    return *reinterpret_cast<unsigned*>(&h);
}

// ---------------------------------------------------------------- fused prep
__global__ void prep_all(const float* __restrict__ x, bf16* __restrict__ xb,
                         const float* __restrict__ ipw, const float* __restrict__ opw,
                         const float* __restrict__ fcw, const float* __restrict__ wloc,
                         bf16* __restrict__ ipwb, bf16* __restrict__ opwb,
                         bf16* __restrict__ fcwb, bf16* __restrict__ wlTb,
                         const int* __restrict__ adj, int* __restrict__ ideg) {
    int b = blockIdx.x, t = threadIdx.x;
    if (b < 2048) {
        for (int i = b * 256 + t; i < NN * CC; i += 2048 * 256) xb[i] = f2bf(x[i]);
    } else if (b < 2816) { int i = (b - 2048) * 256 + t; ipwb[i] = f2bf(ipw[i]); }
    else if (b < 3072)   { int i = (b - 2816) * 256 + t; opwb[i] = f2bf(opw[i]); }
    else if (b < 3328)   { int i = (b - 3072) * 256 + t; fcwb[i] = f2bf(fcw[i]); }
    else if (b < 3584)   { int n = b - 3328;             wlTb[n * 256 + t] = f2bf(wloc[t * 256 + n]); }
    else {
        int e = (b - 3584) * 256 + t;
        if (e < EE) atomicAdd(&ideg[adj[EE + e]], 1);
    }
}

// ---------------------------------------------------------------- K/V fragment prepack (fused)
__global__ __launch_bounds__(256) void build_kv(const bf16* __restrict__ qkv,
                                                bf16* __restrict__ Kpk,
                                                bf16* __restrict__ Vpk) {
    __shared__ bf16 tl[64][72];
    const int bx = blockIdx.x;     // 64-key tile
    const int h  = blockIdx.y;
    const int tid = threadIdx.x;
    // ---- K
    #pragma unroll
    for (int i = 0; i < 2; i++) {
        int u = tid + i * 256;
        int key = u >> 3, g = u & 7;
        *reinterpret_cast<bf16x8*>(&tl[key][g * 8]) =
            *reinterpret_cast<const bf16x8*>(qkv + (size_t)(bx * 64 + key) * 768 + 256 + h * 64 + g * 8);
    }
    __syncthreads();
    #pragma unroll
    for (int i = 0; i < 2; i++) {
        int ee = tid + i * 256;
        int l15 = ee & 15, quad = (ee >> 4) & 3, c = (ee >> 6) & 1, ktl = ee >> 7;
        int key_local = (ktl >> 1) * 32 + (l15 >> 2) * 8 + (ktl & 1) * 4 + (l15 & 3);
        bf16x8 v = *reinterpret_cast<const bf16x8*>(&tl[key_local][c * 32 + quad * 8]);
        *reinterpret_cast<bf16x8*>(Kpk + ((size_t)((h * 512 + bx * 4 + ktl) * 2 + c)) * 512
                                       + (quad * 16 + l15) * 8) = v;
    }
    __syncthreads();
    // ---- V
    #pragma unroll
    for (int i = 0; i < 2; i++) {
        int u = tid + i * 256;
        int key = u >> 3, g = u & 7;
        *reinterpret_cast<bf16x8*>(&tl[key][g * 8]) =
            *reinterpret_cast<const bf16x8*>(qkv + (size_t)(bx * 64 + key) * 768 + 512 + h * 64 + g * 8);
    }
    __syncthreads();
    #pragma unroll
    for (int i = 0; i < 2; i++) {
        int ee = tid + i * 256;
        int l15 = ee & 15, quad = (ee >> 4) & 3, nt = (ee >> 6) & 3, kcl = ee >> 8;
        bf16x8 v;
        #pragma unroll
        for (int j = 0; j < 8; j++) v[j] = tl[kcl * 32 + quad * 8 + j][nt * 16 + l15];
        *reinterpret_cast<bf16x8*>(Vpk + ((size_t)((h * 256 + bx * 2 + kcl) * 4 + nt)) * 512
                                       + (quad * 16 + l15) * 8) = v;
    }
}

// ---------------------------------------------------------------- GCN CSR build
__global__ __launch_bounds__(256) void scan_offsets(const int* __restrict__ ideg,
        int* __restrict__ off, int* __restrict__ cursor, float* __restrict__ rs) {
    __shared__ int ps[256];
    const int tid = threadIdx.x;
    const int base = tid * 32;
    int loc[32];
    int s = 0;
    #pragma unroll
    for (int i = 0; i < 32; i++) { loc[i] = s; s += ideg[base + i]; }
    ps[tid] = s;
    __syncthreads();
    for (int d = 1; d < 256; d <<= 1) {
        int v = (tid >= d) ? ps[tid - d] : 0;
        __syncthreads();
        ps[tid] += v;
        __syncthreads();
    }
    int excl = ps[tid] - s;
    #pragma unroll
    for (int i = 0; i < 32; i++) {
        int o = excl + loc[i];
        off[base + i] = o;
        cursor[base + i] = o;
        int dg = ideg[base + i];
        rs[base + i] = dg > 0 ? rsqrtf((float)dg) : 0.f;
    }
    if (tid == 255) off[8192] = excl + s;
}

__global__ void fill_csr(const int* __restrict__ adj, int* __restrict__ cursor,
                         int* __restrict__ csr) {
    int e = blockIdx.x * 256 + threadIdx.x;
    if (e < EE) {
        int col = adj[EE + e];
        int pos = atomicAdd(&cursor[col], 1);
        csr[pos] = adj[e];
    }
}

// ---------------------------------------------------------------- BT GEMM (qkv)
__global__ __launch_bounds__(256) void gemm_bt(
        const bf16* __restrict__ A, const bf16* __restrict__ W,
        const float* __restrict__ bias,
        float* __restrict__ outF, bf16* __restrict__ outB,
        int M, int N, int K) {
    const int tid  = threadIdx.x;
    const int wave = tid >> 6;
    const int lane = tid & 63;
    const int quad = lane >> 4;
    const int l15  = lane & 15;
    const int m0 = blockIdx.x * 128;
    const int n0 = blockIdx.y * 64;

    __shared__ bf16 Alds[128][72];
    __shared__ bf16 Wlds[64][72];

    f32x4 acc[2][4];
    #pragma unroll
    for (int mt = 0; mt < 2; mt++)
        #pragma unroll
        for (int nt = 0; nt < 4; nt++)
            acc[mt][nt] = (f32x4){0.f, 0.f, 0.f, 0.f};

    for (int k0 = 0; k0 < K; k0 += 64) {
        #pragma unroll
        for (int i = 0; i < 4; i++) {
            int u = tid + i * 256;
            int r = u >> 3;
            int cp = u & 7;
            *reinterpret_cast<bf16x8*>(&Alds[r][cp * 8]) =
                *reinterpret_cast<const bf16x8*>(A + (size_t)(m0 + r) * K + k0 + cp * 8);
        }
        #pragma unroll
        for (int i = 0; i < 2; i++) {
            int u = tid + i * 256;
            int r = u >> 3;
            int cp = u & 7;
            *reinterpret_cast<bf16x8*>(&Wlds[r][cp * 8]) =
                *reinterpret_cast<const bf16x8*>(W + (size_t)(n0 + r) * K + k0 + cp * 8);
        }
        __syncthreads();
        #pragma unroll
        for (int c = 0; c < 2; c++) {
            bf16x8 af[2], wf[4];
            #pragma unroll
            for (int mt = 0; mt < 2; mt++)
                af[mt] = *reinterpret_cast<const bf16x8*>(&Alds[wave * 32 + mt * 16 + l15][c * 32 + quad * 8]);
            #pragma unroll
            for (int nt = 0; nt < 4; nt++)
                wf[nt] = *reinterpret_cast<const bf16x8*>(&Wlds[nt * 16 + l15][c * 32 + quad * 8]);
            #pragma unroll
            for (int mt = 0; mt < 2; mt++)
                #pragma unroll
                for (int nt = 0; nt < 4; nt++)
                    acc[mt][nt] = __builtin_amdgcn_mfma_f32_16x16x32_bf16(af[mt], wf[nt], acc[mt][nt], 0, 0, 0);
        }
        __syncthreads();
    }
    #pragma unroll
    for (int mt = 0; mt < 2; mt++)
        #pragma unroll
        for (int nt = 0; nt < 4; nt++)
            #pragma unroll
            for (int r = 0; r < 4; r++) {
                int m = m0 + wave * 32 + mt * 16 + quad * 4 + r;
                int n = n0 + nt * 16 + l15;
                float v = acc[mt][nt][r];
                if (bias) v += bias[n];
                if (outF) outF[(size_t)m * N + n] = v;
                else      outB[(size_t)m * N + n] = f2bf(v);
            }
}

// ---------------------------------------------------------------- flash + gather fused
// Blocks 0..255: flash_attn10 verbatim (compute-saturated: MFMA+trans ~95% issue).
// Blocks 256..767: GCN CSR gather (memory-latency-bound, no LDS/barriers) rides
// in the second workgroup slot of each CU, hidden under flash (m114 overlap).
__global__ __launch_bounds__(512, 2) void flash_gather(const bf16* __restrict__ qkv,
                                                       const bf16* __restrict__ Kpk,
                                                       const bf16* __restrict__ Vpk,
                                                       bf16* __restrict__ attnO,
                                                       const bf16* __restrict__ xb,
                                                       const int* __restrict__ csr,
                                                       const int* __restrict__ off,
                                                       const float* __restrict__ rs,
                                                       bf16* __restrict__ hib) {
    __shared__ bf16 Osh[8][64][68];
    __shared__ float lsh[8][64];

    if (blockIdx.x >= 256) {
        // ---------------- gather role: 4 groups of 128 threads, 4 nodes/round
        const int gb = blockIdx.x - 256;        // 0..511
        const int grp = threadIdx.x >> 7;       // 0..3
        const int j = threadIdx.x & 127;
        #pragma unroll
        for (int round = 0; round < 4; round++) {
            const int col = gb * 4 + grp + round * 2048;
            const int o = off[col];
            const int cnt = off[col + 1] - o;
            const float rsc = rs[col];
            float a0 = 0.f, a1 = 0.f;
            int e = 0;
            for (; e + 4 <= cnt; e += 4) {
                int r0 = csr[o + e], r1 = csr[o + e + 1], r2 = csr[o + e + 2], r3 = csr[o + e + 3];
                float v0 = rsc * rs[r0], v1 = rsc * rs[r1], v2 = rsc * rs[r2], v3 = rsc * rs[r3];
                unsigned u0 = ((const unsigned*)(xb + (size_t)r0 * CC))[j];
                unsigned u1 = ((const unsigned*)(xb + (size_t)r1 * CC))[j];
                unsigned u2 = ((const unsigned*)(xb + (size_t)r2 * CC))[j];
                unsigned u3 = ((const unsigned*)(xb + (size_t)r3 * CC))[j];
                a0 += __uint_as_float(u0 << 16) * v0 + __uint_as_float(u1 << 16) * v1
                    + __uint_as_float(u2 << 16) * v2 + __uint_as_float(u3 << 16) * v3;
                a1 += __uint_as_float(u0 & 0xffff0000u) * v0 + __uint_as_float(u1 & 0xffff0000u) * v1
                    + __uint_as_float(u2 & 0xffff0000u) * v2 + __uint_as_float(u3 & 0xffff0000u) * v3;
            }
            for (; e < cnt; e++) {
                int r0 = csr[o + e];
                float v0 = rsc * rs[r0];
                unsigned u0 = ((const unsigned*)(xb + (size_t)r0 * CC))[j];
                a0 += __uint_as_float(u0 << 16) * v0;
                a1 += __uint_as_float(u0 & 0xffff0000u) * v0;
            }
            bf16x2 pk; pk[0] = f2bf(a0); pk[1] = f2bf(a1);
            ((bf16x2*)(hib + (size_t)col * CC))[j] = pk;
        }
        return;
    }

    // ---------------- flash role (v10 verbatim)
    const int tid  = threadIdx.x;
    const int w    = tid >> 6;           // 0..7
    const int g    = w >> 2;             // q-group
    const int k4   = w & 3;              // key-split lane within group
    const int lane = tid & 63;
    const int quad = lane >> 4;
    const int l15  = lane & 15;
    const int bx = blockIdx.x;
    const int h  = bx & 3;
    const int qb = bx >> 2;              // 0..63
    const int qbase = qb * 128 + g * 64;

    const float qs = 0.180336880f;
    bf16x8 qf[4][2];
    #pragma unroll
    for (int qt = 0; qt < 4; qt++)
        #pragma unroll
        for (int c = 0; c < 2; c++) {
            bf16x8 raw = *reinterpret_cast<const bf16x8*>(
                qkv + (size_t)(qbase + qt * 16 + l15) * 768 + h * 64 + c * 32 + quad * 8);
            #pragma unroll
            for (int j = 0; j < 8; j++) qf[qt][c][j] = f2bf((float)raw[j] * qs);
        }

    const bf16* Kb = Kpk + (size_t)h * 524288 + lane * 8;
    const bf16* Vb = Vpk + (size_t)h * 524288 + lane * 8;

    f32x4 oacc[4][4];
    #pragma unroll
    for (int qt = 0; qt < 4; qt++)
        #pragma unroll
        for (int nt = 0; nt < 4; nt++) oacc[qt][nt] = (f32x4){0.f, 0.f, 0.f, 0.f};
    f32x4 lacc[4];
    #pragma unroll
    for (int qt = 0; qt < 4; qt++) lacc[qt] = (f32x4){0.f, 0.f, 0.f, 0.f};
    bf16x8 onesf;
    #pragma unroll
    for (int j = 0; j < 8; j++) onesf[j] = f2bf(1.0f);
    const f32x4 z4 = (f32x4){0.f, 0.f, 0.f, 0.f};

    bf16x8 kfA[2][2], vfA[4], kfB[2][2], vfB[4];

    #define LOADKV(kc, kf, vf)                                                          \
        {                                                                               \
            _Pragma("unroll")                                                           \
            for (int s = 0; s < 2; s++)                                                 \
                _Pragma("unroll")                                                       \
                for (int c = 0; c < 2; c++)                                             \
                    kf[s][c] = *reinterpret_cast<const bf16x8*>(Kb + (kc) * 2048 + s * 1024 + c * 512); \
            _Pragma("unroll")                                                           \
            for (int nt = 0; nt < 4; nt++)                                              \
                vf[nt] = *reinterpret_cast<const bf16x8*>(Vb + (kc) * 2048 + nt * 512); \
        }

    #define COMPUTE(kf, vf)                                                             \
        {                                                                               \
            f32x4 sacc[2][4];                                                           \
            _Pragma("unroll")                                                           \
            for (int s = 0; s < 2; s++)                                                 \
                _Pragma("unroll")                                                       \
                for (int qt = 0; qt < 4; qt++) {                                        \
                    sacc[s][qt] = __builtin_amdgcn_mfma_f32_16x16x32_bf16(kf[s][0], qf[qt][0], z4, 0, 0, 0); \
                    sacc[s][qt] = __builtin_amdgcn_mfma_f32_16x16x32_bf16(kf[s][1], qf[qt][1], sacc[s][qt], 0, 0, 0); \
                }                                                                       \
            _Pragma("unroll")                                                           \
            for (int qt = 0; qt < 4; qt++) {                                            \
                float e0 = __builtin_amdgcn_exp2f(sacc[0][qt][0]);                      \
                float e1 = __builtin_amdgcn_exp2f(sacc[0][qt][1]);                      \
                float e2 = __builtin_amdgcn_exp2f(sacc[0][qt][2]);                      \
                float e3 = __builtin_amdgcn_exp2f(sacc[0][qt][3]);                      \
                float e4 = __builtin_amdgcn_exp2f(sacc[1][qt][0]);                      \
                float e5 = __builtin_amdgcn_exp2f(sacc[1][qt][1]);                      \
                float e6 = __builtin_amdgcn_exp2f(sacc[1][qt][2]);                      \
                float e7 = __builtin_amdgcn_exp2f(sacc[1][qt][3]);                      \
                union { bf16x8 v; unsigned u[4]; } pu;                                  \
                pu.u[0] = pk2(e0, e1);                                                  \
                pu.u[1] = pk2(e2, e3);                                                  \
                pu.u[2] = pk2(e4, e5);                                                  \
                pu.u[3] = pk2(e6, e7);                                                  \
                _Pragma("unroll")                                                       \
                for (int nt = 0; nt < 4; nt++)                                          \
                    oacc[qt][nt] = __builtin_amdgcn_mfma_f32_16x16x32_bf16(pu.v, vf[nt], oacc[qt][nt], 0, 0, 0); \
                lacc[qt] = __builtin_amdgcn_mfma_f32_16x16x32_bf16(pu.v, onesf, lacc[qt], 0, 0, 0); \
            }                                                                           \
        }

    LOADKV(k4, kfA, vfA);
    for (int it = 0; it < 64; it += 2) {
        const int kB = k4 + (it + 1) * 4;
        LOADKV(kB, kfB, vfB);
        COMPUTE(kfA, vfA);
        int kA2 = k4 + (it + 2) * 4;
        if (kA2 > 255) kA2 = k4;
        LOADKV(kA2, kfA, vfA);
        COMPUTE(kfB, vfB);
    }
    #undef LOADKV
    #undef COMPUTE

    #pragma unroll
    for (int qt = 0; qt < 4; qt++)
        #pragma unroll
        for (int nt = 0; nt < 4; nt++)
            #pragma unroll
            for (int r = 0; r < 4; r++)
                Osh[w][qt * 16 + quad * 4 + r][nt * 16 + l15] = f2bf(oacc[qt][nt][r]);
    if (l15 == 0) {
        #pragma unroll
        for (int qt = 0; qt < 4; qt++)
            #pragma unroll
            for (int r = 0; r < 4; r++)
                lsh[w][qt * 16 + quad * 4 + r] = lacc[qt][r];
    }
    __syncthreads();

    const int q7 = tid >> 2;             // 0..127
    const int gg = q7 >> 6;
    const int ql = q7 & 63;
    const int ds = (tid & 3) * 16;
    const int wb = gg * 4;
    float lsum = lsh[wb][ql] + lsh[wb + 1][ql] + lsh[wb + 2][ql] + lsh[wb + 3][ql];
    float linv = 1.f / lsum;
    float acc[16];
    #pragma unroll
    for (int i = 0; i < 16; i++) acc[i] = 0.f;
    #pragma unroll
    for (int v = 0; v < 4; v++) {
        bf16x8 o0 = *reinterpret_cast<const bf16x8*>(&Osh[wb + v][ql][ds]);
        bf16x8 o1 = *reinterpret_cast<const bf16x8*>(&Osh[wb + v][ql][ds + 8]);
        #pragma unroll
        for (int i = 0; i < 8; i++) { acc[i] += (float)o0[i]; acc[8 + i] += (float)o1[i]; }
    }
    bf16x8 ob0, ob1;
    #pragma unroll
    for (int i = 0; i < 8; i++) {
        ob0[i] = f2bf(acc[i] * linv);
        ob1[i] = f2bf(acc[8 + i] * linv);
    }
    bf16* dst = attnO + (size_t)(qb * 128 + q7) * CC + h * 64 + ds;
    *reinterpret_cast<bf16x8*>(dst) = ob0;
    *reinterpret_cast<bf16x8*>(dst + 8) = ob1;
}

// ---------------------------------------------------------------- gemm + LN + combine + fc
// Block = 16 rows x all 256 cols (4 waves = 4 col-chunks). Computes
// aprj = aOb@opw^T+opb and locl = hib@wlT^T into registers (f32), LayerNorm
// (x + aprj) with cross-wave LDS reduce, combines with sigmoid(alpha), stores
// comb tile in LDS (bf16), then fc GEMM -> out. Weight frags read direct from
// L2-resident global (no W staging).
__global__ __launch_bounds__(256) void gemm_ln_fc(
        const bf16* __restrict__ aOb, const bf16* __restrict__ opwb, const float* __restrict__ opb,
        const bf16* __restrict__ hib, const bf16* __restrict__ wlTb,
        const float* __restrict__ x, const float* __restrict__ lng, const float* __restrict__ lnb,
        const float* __restrict__ alp, const bf16* __restrict__ fcwb, const float* __restrict__ fcb,
        float* __restrict__ out) {
    const int tid = threadIdx.x;
    const int w = tid >> 6, lane = tid & 63, quad = lane >> 4, l15 = lane & 15;
    const int m0 = blockIdx.x * 16;
    const int n0w = w * 64;
    const f32x4 z4 = (f32x4){0.f, 0.f, 0.f, 0.f};

    __shared__ bf16 Ab[16][264];
    __shared__ float Xl[16][260];
    __shared__ float rsum[4][16], rsq[4][16];

    // stage x tile 16x256 f32
    #pragma unroll
    for (int i = 0; i < 4; i++) {
        int u = tid + i * 256;                     // 0..1023
        int row = u >> 6, cp = (u & 63) * 4;
        *reinterpret_cast<f32x4*>(&Xl[row][cp]) =
            *reinterpret_cast<const f32x4*>(x + (size_t)(m0 + row) * CC + cp);
    }

    // ---- gemm0: aprj tile (A = aOb)
    #pragma unroll
    for (int i = 0; i < 2; i++) {
        int u = tid + i * 256;                     // 0..511
        int row = u >> 5, cp = (u & 31) * 8;
        *reinterpret_cast<bf16x8*>(&Ab[row][cp]) =
            *reinterpret_cast<const bf16x8*>(aOb + (size_t)(m0 + row) * CC + cp);
    }
    __syncthreads();
    f32x4 r0[4], r1[4], acc[4];
    #pragma unroll
    for (int nt = 0; nt < 4; nt++) acc[nt] = z4;
    for (int kc = 0; kc < 4; kc++)
        #pragma unroll
        for (int c = 0; c < 2; c++) {
            bf16x8 af = *reinterpret_cast<const bf16x8*>(&Ab[l15][kc * 64 + c * 32 + quad * 8]);
            #pragma unroll
            for (int nt = 0; nt < 4; nt++) {
                bf16x8 wf = *reinterpret_cast<const bf16x8*>(
                    opwb + (size_t)(n0w + nt * 16 + l15) * CC + kc * 64 + c * 32 + quad * 8);
                acc[nt] = __builtin_amdgcn_mfma_f32_16x16x32_bf16(af, wf, acc[nt], 0, 0, 0);
            }
        }
    #pragma unroll
    for (int nt = 0; nt < 4; nt++) r0[nt] = acc[nt];
    __syncthreads();

    // ---- gemm1: locl tile (A = hib)
    #pragma unroll
    for (int i = 0; i < 2; i++) {
        int u = tid + i * 256;
        int row = u >> 5, cp = (u & 31) * 8;
        *reinterpret_cast<bf16x8*>(&Ab[row][cp]) =
            *reinterpret_cast<const bf16x8*>(hib + (size_t)(m0 + row) * CC + cp);
    }
    __syncthreads();
    #pragma unroll
    for (int nt = 0; nt < 4; nt++) acc[nt] = z4;
    for (int kc = 0; kc < 4; kc++)
        #pragma unroll
        for (int c = 0; c < 2; c++) {
            bf16x8 af = *reinterpret_cast<const bf16x8*>(&Ab[l15][kc * 64 + c * 32 + quad * 8]);
            #pragma unroll
            for (int nt = 0; nt < 4; nt++) {
                bf16x8 wf = *reinterpret_cast<const bf16x8*>(
                    wlTb + (size_t)(n0w + nt * 16 + l15) * CC + kc * 64 + c * 32 + quad * 8);
                acc[nt] = __builtin_amdgcn_mfma_f32_16x16x32_bf16(af, wf, acc[nt], 0, 0, 0);
            }
        }
    #pragma unroll
    for (int nt = 0; nt < 4; nt++) r1[nt] = acc[nt];
    __syncthreads();   // gemm1 A-reads complete before Ab is overwritten with comb

    // ---- LN stats: v = x + aprj; one-pass sum/sumsq
    float v[4][4];
    #pragma unroll
    for (int nt = 0; nt < 4; nt++) {
        float bias0 = opb[n0w + nt * 16 + l15];
        #pragma unroll
        for (int r = 0; r < 4; r++)
            v[nt][r] = Xl[quad * 4 + r][n0w + nt * 16 + l15] + r0[nt][r] + bias0;
    }
    #pragma unroll
    for (int r = 0; r < 4; r++) {
        float s = v[0][r] + v[1][r] + v[2][r] + v[3][r];
        float s2 = v[0][r] * v[0][r] + v[1][r] * v[1][r] + v[2][r] * v[2][r] + v[3][r] * v[3][r];
        #pragma unroll
        for (int o = 1; o < 16; o <<= 1) { s += __shfl_xor(s, o); s2 += __shfl_xor(s2, o); }
        if (l15 == 0) { rsum[w][quad * 4 + r] = s; rsq[w][quad * 4 + r] = s2; }
    }
    __syncthreads();

    const float wgt = 1.f / (1.f + __expf(-alp[0]));
    float gv[4], bv[4], fb[4];
    #pragma unroll
    for (int nt = 0; nt < 4; nt++) {
        int n = n0w + nt * 16 + l15;
        gv[nt] = lng[n]; bv[nt] = lnb[n]; fb[nt] = fcb[n];
    }
    #pragma unroll
    for (int r = 0; r < 4; r++) {
        int row = quad * 4 + r;
        float S = rsum[0][row] + rsum[1][row] + rsum[2][row] + rsum[3][row];
        float S2 = rsq[0][row] + rsq[1][row] + rsq[2][row] + rsq[3][row];
        float mu = S * (1.f / CC);
        float var = S2 * (1.f / CC) - mu * mu;
        float rstd = rsqrtf(var + 1e-5f);
        #pragma unroll
        for (int nt = 0; nt < 4; nt++) {
            float ln = (v[nt][r] - mu) * rstd * gv[nt] + bv[nt];
            float cmb = wgt * r1[nt][r] + (1.f - wgt) * ln;
            Ab[row][n0w + nt * 16 + l15] = f2bf(cmb);
        }
    }
    __syncthreads();

    // ---- fc: out = comb @ fcw^T + fcb
    #pragma unroll
    for (int nt = 0; nt < 4; nt++) acc[nt] = z4;
    for (int kc = 0; kc < 4; kc++)
        #pragma unroll
        for (int c = 0; c < 2; c++) {
            bf16x8 af = *reinterpret_cast<const bf16x8*>(&Ab[l15][kc * 64 + c * 32 + quad * 8]);
            #pragma unroll
            for (int nt = 0; nt < 4; nt++) {
                bf16x8 wf = *reinterpret_cast<const bf16x8*>(
                    fcwb + (size_t)(n0w + nt * 16 + l15) * CC + kc * 64 + c * 32 + quad * 8);
                acc[nt] = __builtin_amdgcn_mfma_f32_16x16x32_bf16(af, wf, acc[nt], 0, 0, 0);
            }
        }
    #pragma unroll
    for (int nt = 0; nt < 4; nt++)
        #pragma unroll
        for (int r = 0; r < 4; r++)
            out[(size_t)(m0 + quad * 4 + r) * CC + n0w + nt * 16 + l15] = acc[nt][r] + fb[nt];
}

// ---------------------------------------------------------------- launch
extern "C" void kernel_launch(void* const* d_in, const int* in_sizes, int n_in,
                              void* d_out, int out_size, void* d_ws, size_t ws_size,
                              hipStream_t stream) {
    (void)in_sizes; (void)n_in; (void)out_size; (void)ws_size;
    const float* x    = (const float*)d_in[0];
    const int*   adj  = (const int*)d_in[1];
    const float* wloc = (const float*)d_in[2];
    const float* ipw  = (const float*)d_in[3];
    const float* ipb  = (const float*)d_in[4];
    const float* opw  = (const float*)d_in[5];
    const float* opb  = (const float*)d_in[6];
    const float* lng  = (const float*)d_in[7];
    const float* lnb  = (const float*)d_in[8];
    const float* alp  = (const float*)d_in[9];
    const float* fcw  = (const float*)d_in[10];
    const float* fcb  = (const float*)d_in[11];
    float* out = (float*)d_out;

    char* p = (char*)d_ws;
    int*   ideg   = (int*)p;    p += (size_t)NN * 4;
    int*   off    = (int*)p;    p += (size_t)(NN + 1) * 4;
    int*   cursor = (int*)p;    p += (size_t)NN * 4;
    float* rs     = (float*)p;  p += (size_t)NN * 4;
    int*   csr    = (int*)p;    p += (size_t)EE * 4;
    bf16* xb    = (bf16*)p;   p += (size_t)NN * CC * 2;
    bf16* hib   = (bf16*)p;   p += (size_t)NN * CC * 2;
    bf16* ipwb  = (bf16*)p;   p += (size_t)768 * 256 * 2;
    bf16* wlTb  = (bf16*)p;   p += (size_t)256 * 256 * 2;
    bf16* opwb  = (bf16*)p;   p += (size_t)256 * 256 * 2;
    bf16* fcwb  = (bf16*)p;   p += (size_t)256 * 256 * 2;
    bf16* qkvb  = (bf16*)p;   p += (size_t)NN * 768 * 2;
    bf16* Kpk   = (bf16*)p;   p += (size_t)HH * 512 * 2 * 512 * 2;
    bf16* Vpk   = (bf16*)p;   p += (size_t)HH * 256 * 4 * 512 * 2;
    bf16* aOb   = (bf16*)p;   p += (size_t)NN * CC * 2;

    hipMemsetAsync(ideg, 0, (size_t)NN * 4, stream);

    prep_all<<<4608, 256, 0, stream>>>(x, xb, ipw, opw, fcw, wloc, ipwb, opwb, fcwb, wlTb, adj, ideg);
    scan_offsets<<<1, 256, 0, stream>>>(ideg, off, cursor, rs);
    fill_csr<<<EE / 256, 256, 0, stream>>>(adj, cursor, csr);

    gemm_bt<<<dim3(NN / 128, 768 / 64), 256, 0, stream>>>(xb, ipwb, ipb, nullptr, qkvb, NN, 768, 256);
    build_kv<<<dim3(NN / 64, HH), 256, 0, stream>>>(qkvb, Kpk, Vpk);
    flash_gather<<<768, 512, 0, stream>>>(qkvb, Kpk, Vpk, aOb, xb, csr, off, rs, hib);
    gemm_ln_fc<<<NN / 16, 256, 0, stream>>>(aOb, opwb, opb, hib, wlTb, x, lng, lnb, alp, fcwb, fcb, out);
}

// Round 12
// 255.185 us; speedup vs baseline: 1.2148x; 1.0839x over previous
//
#include <hip/hip_runtime.h>
#include <hip/hip_bf16.h>
#include <math.h>

#define NN   8192
#define EE   262144
#define CC   256
#define HH   4

typedef __bf16 bf16;
typedef __bf16 bf16x8 __attribute__((ext_vector_type(8)));
typedef __bf16 bf16x4 __attribute__((ext_vector_type(4)));
typedef __bf16 bf16x2 __attribute__((ext_vector_type(2)));
typedef float  f32x4  __attribute__((ext_vector_type(4)));

static __device__ __forceinline__ bf16 f2bf(float f) { return (bf16)f; }

// packed f32x2 -> bf16x2 in one dword (v_cvt_pk_bf16_f32)
static __device__ __forceinline__ unsigned pk2(float a, float b) {
    __hip_bfloat162 h = __float22bfloat162_rn(float2{a, b});
    return *reinterpret_cast<unsigned*>(&h);
}

// ---------------------------------------------------------------- fused prep
__global__ void prep_all(const float* __restrict__ x, bf16* __restrict__ xb,
                         const float* __restrict__ ipw, const float* __restrict__ opw,
                         const float* __restrict__ fcw, const float* __restrict__ wloc,
                         bf16* __restrict__ ipwb, bf16* __restrict__ opwb,
                         bf16* __restrict__ fcwb, bf16* __restrict__ wlTb,
                         const int* __restrict__ adj, int* __restrict__ ideg) {
    int b = blockIdx.x, t = threadIdx.x;
    if (b < 2048) {
        for (int i = b * 256 + t; i < NN * CC; i += 2048 * 256) xb[i] = f2bf(x[i]);
    } else if (b < 2816) { int i = (b - 2048) * 256 + t; ipwb[i] = f2bf(ipw[i]); }
    else if (b < 3072)   { int i = (b - 2816) * 256 + t; opwb[i] = f2bf(opw[i]); }
    else if (b < 3328)   { int i = (b - 3072) * 256 + t; fcwb[i] = f2bf(fcw[i]); }
    else if (b < 3584)   { int n = b - 3328;             wlTb[n * 256 + t] = f2bf(wloc[t * 256 + n]); }
    else {
        int e = (b - 3584) * 256 + t;
        if (e < EE) atomicAdd(&ideg[adj[EE + e]], 1);
    }
}

// ---------------------------------------------------------------- K/V fragment prepack (fused)
__global__ __launch_bounds__(256) void build_kv(const bf16* __restrict__ qkv,
                                                bf16* __restrict__ Kpk,
                                                bf16* __restrict__ Vpk) {
    __shared__ bf16 tl[64][72];
    const int bx = blockIdx.x;     // 64-key tile
    const int h  = blockIdx.y;
    const int tid = threadIdx.x;
    // ---- K
    #pragma unroll
    for (int i = 0; i < 2; i++) {
        int u = tid + i * 256;
        int key = u >> 3, g = u & 7;
        *reinterpret_cast<bf16x8*>(&tl[key][g * 8]) =
            *reinterpret_cast<const bf16x8*>(qkv + (size_t)(bx * 64 + key) * 768 + 256 + h * 64 + g * 8);
    }
    __syncthreads();
    #pragma unroll
    for (int i = 0; i < 2; i++) {
        int ee = tid + i * 256;
        int l15 = ee & 15, quad = (ee >> 4) & 3, c = (ee >> 6) & 1, ktl = ee >> 7;
        int key_local = (ktl >> 1) * 32 + (l15 >> 2) * 8 + (ktl & 1) * 4 + (l15 & 3);
        bf16x8 v = *reinterpret_cast<const bf16x8*>(&tl[key_local][c * 32 + quad * 8]);
        *reinterpret_cast<bf16x8*>(Kpk + ((size_t)((h * 512 + bx * 4 + ktl) * 2 + c)) * 512
                                       + (quad * 16 + l15) * 8) = v;
    }
    __syncthreads();
    // ---- V
    #pragma unroll
    for (int i = 0; i < 2; i++) {
        int u = tid + i * 256;
        int key = u >> 3, g = u & 7;
        *reinterpret_cast<bf16x8*>(&tl[key][g * 8]) =
            *reinterpret_cast<const bf16x8*>(qkv + (size_t)(bx * 64 + key) * 768 + 512 + h * 64 + g * 8);
    }
    __syncthreads();
    #pragma unroll
    for (int i = 0; i < 2; i++) {
        int ee = tid + i * 256;
        int l15 = ee & 15, quad = (ee >> 4) & 3, nt = (ee >> 6) & 3, kcl = ee >> 8;
        bf16x8 v;
        #pragma unroll
        for (int j = 0; j < 8; j++) v[j] = tl[kcl * 32 + quad * 8 + j][nt * 16 + l15];
        *reinterpret_cast<bf16x8*>(Vpk + ((size_t)((h * 256 + bx * 2 + kcl) * 4 + nt)) * 512
                                       + (quad * 16 + l15) * 8) = v;
    }
}

// ---------------------------------------------------------------- GCN CSR build
__global__ __launch_bounds__(256) void scan_offsets(const int* __restrict__ ideg,
        int* __restrict__ off, int* __restrict__ cursor, float* __restrict__ rs) {
    __shared__ int ps[256];
    const int tid = threadIdx.x;
    const int base = tid * 32;
    int loc[32];
    int s = 0;
    #pragma unroll
    for (int i = 0; i < 32; i++) { loc[i] = s; s += ideg[base + i]; }
    ps[tid] = s;
    __syncthreads();
    for (int d = 1; d < 256; d <<= 1) {
        int v = (tid >= d) ? ps[tid - d] : 0;
        __syncthreads();
        ps[tid] += v;
        __syncthreads();
    }
    int excl = ps[tid] - s;
    #pragma unroll
    for (int i = 0; i < 32; i++) {
        int o = excl + loc[i];
        off[base + i] = o;
        cursor[base + i] = o;
        int dg = ideg[base + i];
        rs[base + i] = dg > 0 ? rsqrtf((float)dg) : 0.f;
    }
    if (tid == 255) off[8192] = excl + s;
}

__global__ void fill_csr(const int* __restrict__ adj, int* __restrict__ cursor,
                         int* __restrict__ csr) {
    int e = blockIdx.x * 256 + threadIdx.x;
    if (e < EE) {
        int col = adj[EE + e];
        int pos = atomicAdd(&cursor[col], 1);
        csr[pos] = adj[e];
    }
}

// ---------------------------------------------------------------- GCN gather v3
// block = 2 nodes x 128 dword-lanes; NO LDS, NO barriers. 8-edge unrolled
// batches: 8 independent csr loads -> 8 rs -> 8 x dwords (3 chained latencies
// per 8 edges). 4096 blocks -> 8 blocks/CU, 32 waves of independent chains.
__global__ __launch_bounds__(256) void gcn_gather3(const bf16* __restrict__ xb,
        const int* __restrict__ csr, const int* __restrict__ off,
        const float* __restrict__ rs, bf16* __restrict__ hib) {
    const int node = blockIdx.x * 2 + (threadIdx.x >> 7);
    const int j = threadIdx.x & 127;
    const int o = off[node];
    const int cnt = off[node + 1] - o;
    const float rsc = rs[node];
    const unsigned* xrow = (const unsigned*)xb;
    float a0 = 0.f, a1 = 0.f;
    int e = 0;
    for (; e + 8 <= cnt; e += 8) {
        int r[8];
        float v[8];
        unsigned u[8];
        #pragma unroll
        for (int i = 0; i < 8; i++) r[i] = csr[o + e + i];
        #pragma unroll
        for (int i = 0; i < 8; i++) v[i] = rsc * rs[r[i]];
        #pragma unroll
        for (int i = 0; i < 8; i++) u[i] = xrow[(size_t)r[i] * 128 + j];
        #pragma unroll
        for (int i = 0; i < 8; i++) {
            a0 += __uint_as_float(u[i] << 16) * v[i];
            a1 += __uint_as_float(u[i] & 0xffff0000u) * v[i];
        }
    }
    for (; e < cnt; e++) {
        int r0 = csr[o + e];
        float v0 = rsc * rs[r0];
        unsigned u0 = xrow[(size_t)r0 * 128 + j];
        a0 += __uint_as_float(u0 << 16) * v0;
        a1 += __uint_as_float(u0 & 0xffff0000u) * v0;
    }
    bf16x2 pk;
    pk[0] = f2bf(a0);
    pk[1] = f2bf(a1);
    ((bf16x2*)(hib + (size_t)node * CC))[j] = pk;
}

// ---------------------------------------------------------------- BT GEMM (qkv)
__global__ __launch_bounds__(256) void gemm_bt(
        const bf16* __restrict__ A, const bf16* __restrict__ W,
        const float* __restrict__ bias,
        float* __restrict__ outF, bf16* __restrict__ outB,
        int M, int N, int K) {
    const int tid  = threadIdx.x;
    const int wave = tid >> 6;
    const int lane = tid & 63;
    const int quad = lane >> 4;
    const int l15  = lane & 15;
    const int m0 = blockIdx.x * 128;
    const int n0 = blockIdx.y * 64;

    __shared__ bf16 Alds[128][72];
    __shared__ bf16 Wlds[64][72];

    f32x4 acc[2][4];
    #pragma unroll
    for (int mt = 0; mt < 2; mt++)
        #pragma unroll
        for (int nt = 0; nt < 4; nt++)
            acc[mt][nt] = (f32x4){0.f, 0.f, 0.f, 0.f};

    for (int k0 = 0; k0 < K; k0 += 64) {
        #pragma unroll
        for (int i = 0; i < 4; i++) {
            int u = tid + i * 256;
            int r = u >> 3;
            int cp = u & 7;
            *reinterpret_cast<bf16x8*>(&Alds[r][cp * 8]) =
                *reinterpret_cast<const bf16x8*>(A + (size_t)(m0 + r) * K + k0 + cp * 8);
        }
        #pragma unroll
        for (int i = 0; i < 2; i++) {
            int u = tid + i * 256;
            int r = u >> 3;
            int cp = u & 7;
            *reinterpret_cast<bf16x8*>(&Wlds[r][cp * 8]) =
                *reinterpret_cast<const bf16x8*>(W + (size_t)(n0 + r) * K + k0 + cp * 8);
        }
        __syncthreads();
        #pragma unroll
        for (int c = 0; c < 2; c++) {
            bf16x8 af[2], wf[4];
            #pragma unroll
            for (int mt = 0; mt < 2; mt++)
                af[mt] = *reinterpret_cast<const bf16x8*>(&Alds[wave * 32 + mt * 16 + l15][c * 32 + quad * 8]);
            #pragma unroll
            for (int nt = 0; nt < 4; nt++)
                wf[nt] = *reinterpret_cast<const bf16x8*>(&Wlds[nt * 16 + l15][c * 32 + quad * 8]);
            #pragma unroll
            for (int mt = 0; mt < 2; mt++)
                #pragma unroll
                for (int nt = 0; nt < 4; nt++)
                    acc[mt][nt] = __builtin_amdgcn_mfma_f32_16x16x32_bf16(af[mt], wf[nt], acc[mt][nt], 0, 0, 0);
        }
        __syncthreads();
    }
    #pragma unroll
    for (int mt = 0; mt < 2; mt++)
        #pragma unroll
        for (int nt = 0; nt < 4; nt++)
            #pragma unroll
            for (int r = 0; r < 4; r++) {
                int m = m0 + wave * 32 + mt * 16 + quad * 4 + r;
                int n = n0 + nt * 16 + l15;
                float v = acc[mt][nt][r];
                if (bias) v += bias[n];
                if (outF) outF[(size_t)m * N + n] = v;
                else      outB[(size_t)m * N + n] = f2bf(v);
            }
}

// ---------------------------------------------------------------- flash attention v10
// 512-thread blocks, grid 256 (1 block/CU): block = (head, 128 q) x ALL keys.
// m = 0 softmax, ping-pong double buffer, l via P*(ones) MFMA, direct attnO write.
__global__ __launch_bounds__(512, 2) void flash_attn10(const bf16* __restrict__ qkv,
                                                       const bf16* __restrict__ Kpk,
                                                       const bf16* __restrict__ Vpk,
                                                       bf16* __restrict__ attnO) {
    const int tid  = threadIdx.x;
    const int w    = tid >> 6;           // 0..7
    const int g    = w >> 2;             // q-group
    const int k4   = w & 3;              // key-split lane within group
    const int lane = tid & 63;
    const int quad = lane >> 4;
    const int l15  = lane & 15;
    const int bx = blockIdx.x;
    const int h  = bx & 3;
    const int qb = bx >> 2;              // 0..63
    const int qbase = qb * 128 + g * 64;

    __shared__ bf16 Osh[8][64][68];
    __shared__ float lsh[8][64];

    const float qs = 0.180336880f;
    bf16x8 qf[4][2];
    #pragma unroll
    for (int qt = 0; qt < 4; qt++)
        #pragma unroll
        for (int c = 0; c < 2; c++) {
            bf16x8 raw = *reinterpret_cast<const bf16x8*>(
                qkv + (size_t)(qbase + qt * 16 + l15) * 768 + h * 64 + c * 32 + quad * 8);
            #pragma unroll
            for (int j = 0; j < 8; j++) qf[qt][c][j] = f2bf((float)raw[j] * qs);
        }

    const bf16* Kb = Kpk + (size_t)h * 524288 + lane * 8;
    const bf16* Vb = Vpk + (size_t)h * 524288 + lane * 8;

    f32x4 oacc[4][4];
    #pragma unroll
    for (int qt = 0; qt < 4; qt++)
        #pragma unroll
        for (int nt = 0; nt < 4; nt++) oacc[qt][nt] = (f32x4){0.f, 0.f, 0.f, 0.f};
    f32x4 lacc[4];
    #pragma unroll
    for (int qt = 0; qt < 4; qt++) lacc[qt] = (f32x4){0.f, 0.f, 0.f, 0.f};
    bf16x8 onesf;
    #pragma unroll
    for (int j = 0; j < 8; j++) onesf[j] = f2bf(1.0f);
    const f32x4 z4 = (f32x4){0.f, 0.f, 0.f, 0.f};

    bf16x8 kfA[2][2], vfA[4], kfB[2][2], vfB[4];

    #define LOADKV(kc, kf, vf)                                                          \
        {                                                                               \
            _Pragma("unroll")                                                           \
            for (int s = 0; s < 2; s++)                                                 \
                _Pragma("unroll")                                                       \
                for (int c = 0; c < 2; c++)                                             \
                    kf[s][c] = *reinterpret_cast<const bf16x8*>(Kb + (kc) * 2048 + s * 1024 + c * 512); \
            _Pragma("unroll")                                                           \
            for (int nt = 0; nt < 4; nt++)                                              \
                vf[nt] = *reinterpret_cast<const bf16x8*>(Vb + (kc) * 2048 + nt * 512); \
        }

    #define COMPUTE(kf, vf)                                                             \
        {                                                                               \
            f32x4 sacc[2][4];                                                           \
            _Pragma("unroll")                                                           \
            for (int s = 0; s < 2; s++)                                                 \
                _Pragma("unroll")                                                       \
                for (int qt = 0; qt < 4; qt++) {                                        \
                    sacc[s][qt] = __builtin_amdgcn_mfma_f32_16x16x32_bf16(kf[s][0], qf[qt][0], z4, 0, 0, 0); \
                    sacc[s][qt] = __builtin_amdgcn_mfma_f32_16x16x32_bf16(kf[s][1], qf[qt][1], sacc[s][qt], 0, 0, 0); \
                }                                                                       \
            _Pragma("unroll")                                                           \
            for (int qt = 0; qt < 4; qt++) {                                            \
                float e0 = __builtin_amdgcn_exp2f(sacc[0][qt][0]);                      \
                float e1 = __builtin_amdgcn_exp2f(sacc[0][qt][1]);                      \
                float e2 = __builtin_amdgcn_exp2f(sacc[0][qt][2]);                      \
                float e3 = __builtin_amdgcn_exp2f(sacc[0][qt][3]);                      \
                float e4 = __builtin_amdgcn_exp2f(sacc[1][qt][0]);                      \
                float e5 = __builtin_amdgcn_exp2f(sacc[1][qt][1]);                      \
                float e6 = __builtin_amdgcn_exp2f(sacc[1][qt][2]);                      \
                float e7 = __builtin_amdgcn_exp2f(sacc[1][qt][3]);                      \
                union { bf16x8 v; unsigned u[4]; } pu;                                  \
                pu.u[0] = pk2(e0, e1);                                                  \
                pu.u[1] = pk2(e2, e3);                                                  \
                pu.u[2] = pk2(e4, e5);                                                  \
                pu.u[3] = pk2(e6, e7);                                                  \
                _Pragma("unroll")                                                       \
                for (int nt = 0; nt < 4; nt++)                                          \
                    oacc[qt][nt] = __builtin_amdgcn_mfma_f32_16x16x32_bf16(pu.v, vf[nt], oacc[qt][nt], 0, 0, 0); \
                lacc[qt] = __builtin_amdgcn_mfma_f32_16x16x32_bf16(pu.v, onesf, lacc[qt], 0, 0, 0); \
            }                                                                           \
        }

    LOADKV(k4, kfA, vfA);
    for (int it = 0; it < 64; it += 2) {
        const int kB = k4 + (it + 1) * 4;
        LOADKV(kB, kfB, vfB);
        COMPUTE(kfA, vfA);
        int kA2 = k4 + (it + 2) * 4;
        if (kA2 > 255) kA2 = k4;
        LOADKV(kA2, kfA, vfA);
        COMPUTE(kfB, vfB);
    }
    #undef LOADKV
    #undef COMPUTE

    #pragma unroll
    for (int qt = 0; qt < 4; qt++)
        #pragma unroll
        for (int nt = 0; nt < 4; nt++)
            #pragma unroll
            for (int r = 0; r < 4; r++)
                Osh[w][qt * 16 + quad * 4 + r][nt * 16 + l15] = f2bf(oacc[qt][nt][r]);
    if (l15 == 0) {
        #pragma unroll
        for (int qt = 0; qt < 4; qt++)
            #pragma unroll
            for (int r = 0; r < 4; r++)
                lsh[w][qt * 16 + quad * 4 + r] = lacc[qt][r];
    }
    __syncthreads();

    const int q7 = tid >> 2;             // 0..127
    const int gg = q7 >> 6;
    const int ql = q7 & 63;
    const int ds = (tid & 3) * 16;
    const int wb = gg * 4;
    float lsum = lsh[wb][ql] + lsh[wb + 1][ql] + lsh[wb + 2][ql] + lsh[wb + 3][ql];
    float linv = 1.f / lsum;
    float acc[16];
    #pragma unroll
    for (int i = 0; i < 16; i++) acc[i] = 0.f;
    #pragma unroll
    for (int v = 0; v < 4; v++) {
        bf16x8 o0 = *reinterpret_cast<const bf16x8*>(&Osh[wb + v][ql][ds]);
        bf16x8 o1 = *reinterpret_cast<const bf16x8*>(&Osh[wb + v][ql][ds + 8]);
        #pragma unroll
        for (int i = 0; i < 8; i++) { acc[i] += (float)o0[i]; acc[8 + i] += (float)o1[i]; }
    }
    bf16x8 ob0, ob1;
    #pragma unroll
    for (int i = 0; i < 8; i++) {
        ob0[i] = f2bf(acc[i] * linv);
        ob1[i] = f2bf(acc[8 + i] * linv);
    }
    bf16* dst = attnO + (size_t)(qb * 128 + q7) * CC + h * 64 + ds;
    *reinterpret_cast<bf16x8*>(dst) = ob0;
    *reinterpret_cast<bf16x8*>(dst + 8) = ob1;
}

// ---------------------------------------------------------------- gemm + LN + combine + fc
__global__ __launch_bounds__(256) void gemm_ln_fc(
        const bf16* __restrict__ aOb, const bf16* __restrict__ opwb, const float* __restrict__ opb,
        const bf16* __restrict__ hib, const bf16* __restrict__ wlTb,
        const float* __restrict__ x, const float* __restrict__ lng, const float* __restrict__ lnb,
        const float* __restrict__ alp, const bf16* __restrict__ fcwb, const float* __restrict__ fcb,
        float* __restrict__ out) {
    const int tid = threadIdx.x;
    const int w = tid >> 6, lane = tid & 63, quad = lane >> 4, l15 = lane & 15;
    const int m0 = blockIdx.x * 16;
    const int n0w = w * 64;
    const f32x4 z4 = (f32x4){0.f, 0.f, 0.f, 0.f};

    __shared__ bf16 Ab[16][264];
    __shared__ float Xl[16][260];
    __shared__ float rsum[4][16], rsq[4][16];

    #pragma unroll
    for (int i = 0; i < 4; i++) {
        int u = tid + i * 256;
        int row = u >> 6, cp = (u & 63) * 4;
        *reinterpret_cast<f32x4*>(&Xl[row][cp]) =
            *reinterpret_cast<const f32x4*>(x + (size_t)(m0 + row) * CC + cp);
    }

    // ---- gemm0: aprj tile (A = aOb)
    #pragma unroll
    for (int i = 0; i < 2; i++) {
        int u = tid + i * 256;
        int row = u >> 5, cp = (u & 31) * 8;
        *reinterpret_cast<bf16x8*>(&Ab[row][cp]) =
            *reinterpret_cast<const bf16x8*>(aOb + (size_t)(m0 + row) * CC + cp);
    }
    __syncthreads();
    f32x4 r0[4], r1[4], acc[4];
    #pragma unroll
    for (int nt = 0; nt < 4; nt++) acc[nt] = z4;
    for (int kc = 0; kc < 4; kc++)
        #pragma unroll
        for (int c = 0; c < 2; c++) {
            bf16x8 af = *reinterpret_cast<const bf16x8*>(&Ab[l15][kc * 64 + c * 32 + quad * 8]);
            #pragma unroll
            for (int nt = 0; nt < 4; nt++) {
                bf16x8 wf = *reinterpret_cast<const bf16x8*>(
                    opwb + (size_t)(n0w + nt * 16 + l15) * CC + kc * 64 + c * 32 + quad * 8);
                acc[nt] = __builtin_amdgcn_mfma_f32_16x16x32_bf16(af, wf, acc[nt], 0, 0, 0);
            }
        }
    #pragma unroll
    for (int nt = 0; nt < 4; nt++) r0[nt] = acc[nt];
    __syncthreads();

    // ---- gemm1: locl tile (A = hib)
    #pragma unroll
    for (int i = 0; i < 2; i++) {
        int u = tid + i * 256;
        int row = u >> 5, cp = (u & 31) * 8;
        *reinterpret_cast<bf16x8*>(&Ab[row][cp]) =
            *reinterpret_cast<const bf16x8*>(hib + (size_t)(m0 + row) * CC + cp);
    }
    __syncthreads();
    #pragma unroll
    for (int nt = 0; nt < 4; nt++) acc[nt] = z4;
    for (int kc = 0; kc < 4; kc++)
        #pragma unroll
        for (int c = 0; c < 2; c++) {
            bf16x8 af = *reinterpret_cast<const bf16x8*>(&Ab[l15][kc * 64 + c * 32 + quad * 8]);
            #pragma unroll
            for (int nt = 0; nt < 4; nt++) {
                bf16x8 wf = *reinterpret_cast<const bf16x8*>(
                    wlTb + (size_t)(n0w + nt * 16 + l15) * CC + kc * 64 + c * 32 + quad * 8);
                acc[nt] = __builtin_amdgcn_mfma_f32_16x16x32_bf16(af, wf, acc[nt], 0, 0, 0);
            }
        }
    #pragma unroll
    for (int nt = 0; nt < 4; nt++) r1[nt] = acc[nt];
    __syncthreads();

    // ---- LN stats
    float v[4][4];
    #pragma unroll
    for (int nt = 0; nt < 4; nt++) {
        float bias0 = opb[n0w + nt * 16 + l15];
        #pragma unroll
        for (int r = 0; r < 4; r++)
            v[nt][r] = Xl[quad * 4 + r][n0w + nt * 16 + l15] + r0[nt][r] + bias0;
    }
    #pragma unroll
    for (int r = 0; r < 4; r++) {
        float s = v[0][r] + v[1][r] + v[2][r] + v[3][r];
        float s2 = v[0][r] * v[0][r] + v[1][r] * v[1][r] + v[2][r] * v[2][r] + v[3][r] * v[3][r];
        #pragma unroll
        for (int o = 1; o < 16; o <<= 1) { s += __shfl_xor(s, o); s2 += __shfl_xor(s2, o); }
        if (l15 == 0) { rsum[w][quad * 4 + r] = s; rsq[w][quad * 4 + r] = s2; }
    }
    __syncthreads();

    const float wgt = 1.f / (1.f + __expf(-alp[0]));
    float gv[4], bv[4], fb[4];
    #pragma unroll
    for (int nt = 0; nt < 4; nt++) {
        int n = n0w + nt * 16 + l15;
        gv[nt] = lng[n]; bv[nt] = lnb[n]; fb[nt] = fcb[n];
    }
    #pragma unroll
    for (int r = 0; r < 4; r++) {
        int row = quad * 4 + r;
        float S = rsum[0][row] + rsum[1][row] + rsum[2][row] + rsum[3][row];
        float S2 = rsq[0][row] + rsq[1][row] + rsq[2][row] + rsq[3][row];
        float mu = S * (1.f / CC);
        float var = S2 * (1.f / CC) - mu * mu;
        float rstd = rsqrtf(var + 1e-5f);
        #pragma unroll
        for (int nt = 0; nt < 4; nt++) {
            float ln = (v[nt][r] - mu) * rstd * gv[nt] + bv[nt];
            float cmb = wgt * r1[nt][r] + (1.f - wgt) * ln;
            Ab[row][n0w + nt * 16 + l15] = f2bf(cmb);
        }
    }
    __syncthreads();

    // ---- fc: out = comb @ fcw^T + fcb
    #pragma unroll
    for (int nt = 0; nt < 4; nt++) acc[nt] = z4;
    for (int kc = 0; kc < 4; kc++)
        #pragma unroll
        for (int c = 0; c < 2; c++) {
            bf16x8 af = *reinterpret_cast<const bf16x8*>(&Ab[l15][kc * 64 + c * 32 + quad * 8]);
            #pragma unroll
            for (int nt = 0; nt < 4; nt++) {
                bf16x8 wf = *reinterpret_cast<const bf16x8*>(
                    fcwb + (size_t)(n0w + nt * 16 + l15) * CC + kc * 64 + c * 32 + quad * 8);
                acc[nt] = __builtin_amdgcn_mfma_f32_16x16x32_bf16(af, wf, acc[nt], 0, 0, 0);
            }
        }
    #pragma unroll
    for (int nt = 0; nt < 4; nt++)
        #pragma unroll
        for (int r = 0; r < 4; r++)
            out[(size_t)(m0 + quad * 4 + r) * CC + n0w + nt * 16 + l15] = acc[nt][r] + fb[nt];
}

// ---------------------------------------------------------------- launch
extern "C" void kernel_launch(void* const* d_in, const int* in_sizes, int n_in,
                              void* d_out, int out_size, void* d_ws, size_t ws_size,
                              hipStream_t stream) {
    (void)in_sizes; (void)n_in; (void)out_size; (void)ws_size;
    const float* x    = (const float*)d_in[0];
    const int*   adj  = (const int*)d_in[1];
    const float* wloc = (const float*)d_in[2];
    const float* ipw  = (const float*)d_in[3];
    const float* ipb  = (const float*)d_in[4];
    const float* opw  = (const float*)d_in[5];
    const float* opb  = (const float*)d_in[6];
    const float* lng  = (const float*)d_in[7];
    const float* lnb  = (const float*)d_in[8];
    const float* alp  = (const float*)d_in[9];
    const float* fcw  = (const float*)d_in[10];
    const float* fcb  = (const float*)d_in[11];
    float* out = (float*)d_out;

    char* p = (char*)d_ws;
    int*   ideg   = (int*)p;    p += (size_t)NN * 4;
    int*   off    = (int*)p;    p += (size_t)(NN + 1) * 4;
    int*   cursor = (int*)p;    p += (size_t)NN * 4;
    float* rs     = (float*)p;  p += (size_t)NN * 4;
    int*   csr    = (int*)p;    p += (size_t)EE * 4;
    bf16* xb    = (bf16*)p;   p += (size_t)NN * CC * 2;
    bf16* hib   = (bf16*)p;   p += (size_t)NN * CC * 2;
    bf16* ipwb  = (bf16*)p;   p += (size_t)768 * 256 * 2;
    bf16* wlTb  = (bf16*)p;   p += (size_t)256 * 256 * 2;
    bf16* opwb  = (bf16*)p;   p += (size_t)256 * 256 * 2;
    bf16* fcwb  = (bf16*)p;   p += (size_t)256 * 256 * 2;
    bf16* qkvb  = (bf16*)p;   p += (size_t)NN * 768 * 2;
    bf16* Kpk   = (bf16*)p;   p += (size_t)HH * 512 * 2 * 512 * 2;
    bf16* Vpk   = (bf16*)p;   p += (size_t)HH * 256 * 4 * 512 * 2;
    bf16* aOb   = (bf16*)p;   p += (size_t)NN * CC * 2;

    hipMemsetAsync(ideg, 0, (size_t)NN * 4, stream);

    prep_all<<<4608, 256, 0, stream>>>(x, xb, ipw, opw, fcw, wloc, ipwb, opwb, fcwb, wlTb, adj, ideg);
    scan_offsets<<<1, 256, 0, stream>>>(ideg, off, cursor, rs);
    fill_csr<<<EE / 256, 256, 0, stream>>>(adj, cursor, csr);
    gcn_gather3<<<NN / 2, 256, 0, stream>>>(xb, csr, off, rs, hib);

    gemm_bt<<<dim3(NN / 128, 768 / 64), 256, 0, stream>>>(xb, ipwb, ipb, nullptr, qkvb, NN, 768, 256);
    build_kv<<<dim3(NN / 64, HH), 256, 0, stream>>>(qkvb, Kpk, Vpk);
    flash_attn10<<<256, 512, 0, stream>>>(qkvb, Kpk, Vpk, aOb);
    gemm_ln_fc<<<NN / 16, 256, 0, stream>>>(aOb, opwb, opb, hib, wlTb, x, lng, lnb, alp, fcwb, fcb, out);
}